// Round 3
// baseline (12895.930 us; speedup 1.0000x reference)
//
#include <hip/hip_runtime.h>
#include <stdint.h>

#define NB   8
#define NPTS 4096
#define CINV 64
#define MC   1024
#define KNB  64
#define NE   (NB*MC*KNB)
#define K1   67
#define CH1  64
#define CH2  64
#define CH3  128

typedef unsigned short u16;
typedef unsigned int   u32;
typedef unsigned long long u64;

static __device__ __forceinline__ float bf2f(u16 b){ return __uint_as_float(((u32)b)<<16); }
static __device__ __forceinline__ u16  f2bf(float f){
  u32 u = __float_as_uint(f);
  return (u16)((u + 0x7fffu + ((u>>16)&1u)) >> 16);
}
// Exact replica of reference distance: square each diff, sum as (x+y)+z, NO fma contraction.
static __device__ __forceinline__ float d2ref(float ax,float ay,float az,
                                              float bx,float by,float bz){
  float dx = ax-bx, dy = ay-by, dz = az-bz;
  return __fadd_rn(__fadd_rn(__fmul_rn(dx,dx), __fmul_rn(dy,dy)), __fmul_rn(dz,dz));
}

// ---------------------------------------------------------------- FPS
__global__ __launch_bounds__(512) void k_fps(const float* __restrict__ pos,
                                             float* __restrict__ centf,
                                             float* __restrict__ out_cent,
                                             float* __restrict__ out_bsel) {
  __shared__ float px[NPTS], py[NPTS], pz[NPTS];
  __shared__ float redv[8];
  __shared__ int   redi[8];
  __shared__ int   sIdx[MC];
  const int b = blockIdx.x, tid = threadIdx.x;
  for (int i = tid; i < NPTS; i += 512) {
    size_t o = ((size_t)b*NPTS + i)*3;
    px[i] = pos[o]; py[i] = pos[o+1]; pz[i] = pos[o+2];
  }
  if (tid == 0) sIdx[0] = 0;
  __syncthreads();

  float cxr[8], cyr[8], czr[8], dist[8];
  #pragma unroll
  for (int j = 0; j < 8; ++j) {
    int p = tid*8 + j;
    cxr[j] = px[p]; cyr[j] = py[p]; czr[j] = pz[p];
    dist[j] = 1e10f;
  }
  int last = 0;
  const int lane = tid & 63, w = tid >> 6;

  for (int it = 1; it < MC; ++it) {
    const float qx = px[last], qy = py[last], qz = pz[last];
    float bv = -1.f; int bi = 0;
    #pragma unroll
    for (int j = 0; j < 8; ++j) {
      float d  = d2ref(cxr[j], cyr[j], czr[j], qx, qy, qz);
      float nd = fminf(dist[j], d);
      dist[j] = nd;
      if (nd > bv) { bv = nd; bi = tid*8 + j; }   // strict > keeps lowest index
    }
    #pragma unroll
    for (int off = 32; off > 0; off >>= 1) {
      float ov = __shfl_xor(bv, off);
      int   oi = __shfl_xor(bi, off);
      if (ov > bv || (ov == bv && oi < bi)) { bv = ov; bi = oi; }
    }
    if (lane == 0) { redv[w] = bv; redi[w] = bi; }
    __syncthreads();
    bv = redv[0]; bi = redi[0];
    #pragma unroll
    for (int q = 1; q < 8; ++q) {
      float ov = redv[q]; int oi = redi[q];
      if (ov > bv || (ov == bv && oi < bi)) { bv = ov; bi = oi; }
    }
    last = bi;
    if (tid == 0) sIdx[it] = last;
    __syncthreads();
  }

  for (int m = tid; m < MC; m += 512) {
    int i = sIdx[m];
    int r = b*MC + m;
    float qx = px[i], qy = py[i], qz = pz[i];
    centf[r*3+0] = qx; centf[r*3+1] = qy; centf[r*3+2] = qz;
    out_cent[r*3+0] = qx; out_cent[r*3+1] = qy; out_cent[r*3+2] = qz;
    out_bsel[r] = (float)b;
  }
}

// ---------------------------------------------------------------- ball query (top-64 within R)
#define CAP 2048
__global__ __launch_bounds__(256) void k_ball(const float* __restrict__ pos,
                                              const float* __restrict__ centf,
                                              int* __restrict__ nbr,
                                              int* __restrict__ cntpc,
                                              int* __restrict__ cnt_total) {
  __shared__ u64 keys[CAP];
  __shared__ int scnt;
  const int bm = blockIdx.x, tid = threadIdx.x;
  const int b = bm >> 10;
  if (tid == 0) scnt = 0;
  __syncthreads();
  const float cx = centf[bm*3], cy = centf[bm*3+1], cz = centf[bm*3+2];
  for (int i = tid; i < NPTS; i += 256) {
    size_t o = ((size_t)b*NPTS + i)*3;
    float d = d2ref(cx, cy, cz, pos[o], pos[o+1], pos[o+2]);
    if (d <= 0.04f) {
      int p = atomicAdd(&scnt, 1);
      if (p < CAP) keys[p] = ((u64)__float_as_uint(d) << 32) | (u32)i;
    }
  }
  __syncthreads();
  int n = scnt; if (n > CAP) n = CAP;
  int P = 64; while (P < n) P <<= 1;
  for (int i = n + tid; i < P; i += 256) keys[i] = ~0ull;
  __syncthreads();
  for (int ks = 2; ks <= P; ks <<= 1)
    for (int js = ks >> 1; js > 0; js >>= 1) {
      for (int i = tid; i < P; i += 256) {
        int l = i ^ js;
        if (l > i) {
          u64 a = keys[i], c = keys[l];
          bool up = ((i & ks) == 0);
          if ((a > c) == up) { keys[i] = c; keys[l] = a; }
        }
      }
      __syncthreads();
    }
  int c = n < KNB ? n : KNB;
  if (tid < KNB) nbr[(size_t)bm*KNB + tid] = (tid < c) ? (int)(u32)(keys[tid] & 0xffffffffu) : 0;
  if (tid == 0) { cntpc[bm] = c; atomicAdd(cnt_total, c); }
}

// ---------------------------------------------------------------- chain helpers
static __device__ __forceinline__ float wsum(float v){
  #pragma unroll
  for (int off = 32; off > 0; off >>= 1) v += __shfl_xor(v, off);
  return v;
}
static __device__ __forceinline__ float wmax(float v){
  #pragma unroll
  for (int off = 32; off > 0; off >>= 1) v = fmaxf(v, __shfl_xor(v, off));
  return v;
}

// acc[j] = sum_k h[k] * W[k*CO + c0 + j], j in [0,16). W in LDS, broadcast reads.
template<int KD, int CO, int HN>
static __device__ __forceinline__ void gtile(const float* __restrict__ Ws,
                                             const float (&h)[HN], int c0,
                                             float (&acc)[16]) {
  #pragma unroll
  for (int j = 0; j < 16; ++j) acc[j] = 0.f;
  #pragma unroll
  for (int k = 0; k < KD; ++k) {
    const float4* w4 = (const float4*)(Ws + k*CO + c0);
    float4 a = w4[0], bq = w4[1], cq = w4[2], dq = w4[3];
    float hk = h[k];
    acc[ 0] = fmaf(hk, a.x,  acc[ 0]); acc[ 1] = fmaf(hk, a.y,  acc[ 1]);
    acc[ 2] = fmaf(hk, a.z,  acc[ 2]); acc[ 3] = fmaf(hk, a.w,  acc[ 3]);
    acc[ 4] = fmaf(hk, bq.x, acc[ 4]); acc[ 5] = fmaf(hk, bq.y, acc[ 5]);
    acc[ 6] = fmaf(hk, bq.z, acc[ 6]); acc[ 7] = fmaf(hk, bq.w, acc[ 7]);
    acc[ 8] = fmaf(hk, cq.x, acc[ 8]); acc[ 9] = fmaf(hk, cq.y, acc[ 9]);
    acc[10] = fmaf(hk, cq.z, acc[10]); acc[11] = fmaf(hk, cq.w, acc[11]);
    acc[12] = fmaf(hk, dq.x, acc[12]); acc[13] = fmaf(hk, dq.y, acc[13]);
    acc[14] = fmaf(hk, dq.z, acc[14]); acc[15] = fmaf(hk, dq.w, acc[15]);
  }
}

struct CA {
  const float *x, *pos;
  const float *centf;
  const int *nbr, *cntpc;
  const float *W1f, *W2f, *W3f;
  const float *SC;          // A1(64) B1(64) A2(64) B2(64) A3(128) B3(128)
  float *S, *Q;
  u16 *y1g, *y2g;
  float *out0;
};

// One wave = one centroid (64 edges); block = 4 centroids.
template<int STAGE, bool USEY>
__global__ __launch_bounds__(256) void k_stage(CA A) {
  constexpr int W1N = K1*CH1, W2N = CH1*CH2, W3N = CH2*CH3;
  constexpr bool nW1 = (STAGE == 1) || !USEY;
  constexpr bool nW2 = (STAGE >= 2) && (!USEY || STAGE == 2);
  constexpr bool nW3 = (STAGE >= 3);
  constexpr int W1o = 0;
  constexpr int W2o = nW1 ? W1N : 0;
  constexpr int W3o = W2o + (nW2 ? W2N : 0);
  constexpr int WT  = W3o + (nW3 ? W3N : 0);
  __shared__ __align__(16) float Ws[WT + 512];
  __shared__ float red[4][32];
  float* AB = Ws + WT;

  const int tid = threadIdx.x, lane = tid & 63, w = tid >> 6;
  const int bm = blockIdx.x*4 + w;
  const int e  = bm*KNB + lane;
  const int b  = bm >> 10;
  const bool valid = lane < A.cntpc[bm];

  if (nW1) for (int i = tid; i < W1N; i += 256) Ws[W1o + i] = A.W1f[i];
  if (nW2) for (int i = tid; i < W2N; i += 256) Ws[W2o + i] = A.W2f[i];
  if (nW3) for (int i = tid; i < W3N; i += 256) Ws[W3o + i] = A.W3f[i];
  for (int i = tid; i < 512; i += 256) AB[i] = A.SC[i];
  __syncthreads();

  // ---- stage-1 features (only when needed)
  float hbuf[K1];
  if constexpr (STAGE == 1 || !USEY) {
    const int i = A.nbr[e];
    const float4* xr = (const float4*)(A.x + ((size_t)(b*NPTS + i))*CINV);
    #pragma unroll
    for (int c4 = 0; c4 < 16; ++c4) {
      float4 v = xr[c4];
      hbuf[c4*4+0] = v.x; hbuf[c4*4+1] = v.y;
      hbuf[c4*4+2] = v.z; hbuf[c4*4+3] = v.w;
    }
    size_t po = ((size_t)(b*NPTS + i))*3;
    hbuf[64] = A.pos[po+0] - A.centf[bm*3+0];
    hbuf[65] = A.pos[po+1] - A.centf[bm*3+1];
    hbuf[66] = A.pos[po+2] - A.centf[bm*3+2];
  }

  auto tile_stats = [&](const float (&acc)[16], int c0) {
    #pragma unroll
    for (int j = 0; j < 16; ++j) {
      float v = valid ? acc[j] : 0.f;
      float s = wsum(v);
      float q = wsum(v*v);
      if (lane == 0) { red[w][j] = s; red[w][16+j] = q; }
    }
    __syncthreads();
    if (tid < 32) {
      float v = red[0][tid] + red[1][tid] + red[2][tid] + red[3][tid];
      if (tid < 16) atomicAdd(&A.S[c0 + tid], v);
      else          atomicAdd(&A.Q[c0 + tid - 16], v);
    }
    __syncthreads();
  };

  if constexpr (STAGE == 1) {
    #pragma unroll
    for (int t = 0; t < 4; ++t) {
      float acc[16];
      gtile<K1, CH1, K1>(Ws + W1o, hbuf, t*16, acc);
      if constexpr (USEY) {
        u32* dst = (u32*)(A.y1g + (size_t)e*CH1 + t*16);
        #pragma unroll
        for (int j = 0; j < 8; ++j)
          dst[j] = (u32)f2bf(acc[2*j]) | ((u32)f2bf(acc[2*j+1]) << 16);
      }
      tile_stats(acc, t*16);
    }
    return;
  }

  // ---- h2 = bn1(y1) (stages >= 2)
  float h2[CH1];
  if constexpr (USEY) {
    const ushort4* yr = (const ushort4*)(A.y1g + (size_t)e*CH1);
    #pragma unroll
    for (int c4 = 0; c4 < 16; ++c4) {
      ushort4 v = yr[c4];
      h2[c4*4+0] = bf2f(v.x); h2[c4*4+1] = bf2f(v.y);
      h2[c4*4+2] = bf2f(v.z); h2[c4*4+3] = bf2f(v.w);
    }
  } else {
    #pragma unroll
    for (int t = 0; t < 4; ++t) {
      float acc[16];
      gtile<K1, CH1, K1>(Ws + W1o, hbuf, t*16, acc);
      #pragma unroll
      for (int j = 0; j < 16; ++j) h2[t*16+j] = acc[j];
    }
  }
  #pragma unroll
  for (int c = 0; c < CH1; ++c)
    h2[c] = fmaxf(fmaf(h2[c], AB[c], AB[64+c]), 0.f);

  if constexpr (STAGE == 2) {
    #pragma unroll
    for (int t = 0; t < 4; ++t) {
      float acc[16];
      gtile<CH1, CH2, CH1>(Ws + W2o, h2, t*16, acc);
      if constexpr (USEY) {
        u32* dst = (u32*)(A.y2g + (size_t)e*CH2 + t*16);
        #pragma unroll
        for (int j = 0; j < 8; ++j)
          dst[j] = (u32)f2bf(acc[2*j]) | ((u32)f2bf(acc[2*j+1]) << 16);
      }
      tile_stats(acc, t*16);
    }
    return;
  }

  // ---- h3 = bn2(y2) (stages >= 3)
  float h3[CH2];
  if constexpr (USEY) {
    const ushort4* yr = (const ushort4*)(A.y2g + (size_t)e*CH2);
    #pragma unroll
    for (int c4 = 0; c4 < 16; ++c4) {
      ushort4 v = yr[c4];
      h3[c4*4+0] = bf2f(v.x); h3[c4*4+1] = bf2f(v.y);
      h3[c4*4+2] = bf2f(v.z); h3[c4*4+3] = bf2f(v.w);
    }
  } else {
    #pragma unroll
    for (int t = 0; t < 4; ++t) {
      float acc[16];
      gtile<CH1, CH2, CH1>(Ws + W2o, h2, t*16, acc);
      #pragma unroll
      for (int j = 0; j < 16; ++j) h3[t*16+j] = acc[j];
    }
  }
  #pragma unroll
  for (int c = 0; c < CH2; ++c)
    h3[c] = fmaxf(fmaf(h3[c], AB[128+c], AB[192+c]), 0.f);

  if constexpr (STAGE == 3) {
    #pragma unroll
    for (int t = 0; t < 8; ++t) {
      float acc[16];
      gtile<CH2, CH3, CH2>(Ws + W3o, h3, t*16, acc);
      tile_stats(acc, t*16);
    }
    return;
  }

  // ---- STAGE 4: y3 -> bn3 -> relu -> masked max over 64 edges -> out
  #pragma unroll
  for (int t = 0; t < 8; ++t) {
    float acc[16];
    gtile<CH2, CH3, CH2>(Ws + W3o, h3, t*16, acc);
    float mx[16];
    #pragma unroll
    for (int j = 0; j < 16; ++j) {
      int c = t*16 + j;
      float v = fmaxf(fmaf(acc[j], AB[256+c], AB[384+c]), 0.f);
      mx[j] = wmax(valid ? v : -1e30f);
    }
    if (lane == 0) {
      float4* dst = (float4*)(A.out0 + (size_t)bm*CH3 + t*16);
      dst[0] = make_float4(mx[ 0], mx[ 1], mx[ 2], mx[ 3]);
      dst[1] = make_float4(mx[ 4], mx[ 5], mx[ 6], mx[ 7]);
      dst[2] = make_float4(mx[ 8], mx[ 9], mx[10], mx[11]);
      dst[3] = make_float4(mx[12], mx[13], mx[14], mx[15]);
    }
  }
}

// ---------------------------------------------------------------- small kernels
__global__ void k_finalize(const float* __restrict__ S, const float* __restrict__ Q,
                           const float* __restrict__ g, const float* __restrict__ bb,
                           const int* __restrict__ cnt_total,
                           float* __restrict__ Aout, float* __restrict__ Bout, int C) {
  int c = threadIdx.x;
  if (c < C) {
    float n = (float)(*cnt_total); if (n < 1.f) n = 1.f;
    float mu  = S[c] / n;
    float var = Q[c] / n - mu*mu; if (var < 0.f) var = 0.f;
    float inv = 1.0f / sqrtf(var + 1e-5f);
    float a = g[c] * inv;
    Aout[c] = a;
    Bout[c] = bb[c] - mu*a;
  }
}

// ---------------------------------------------------------------- host
extern "C" void kernel_launch(void* const* d_in, const int* in_sizes, int n_in,
                              void* d_out, int out_size, void* d_ws, size_t ws_size,
                              hipStream_t stream) {
  (void)in_sizes; (void)n_in; (void)out_size;
  const float* x   = (const float*)d_in[0];
  const float* pos = (const float*)d_in[1];
  const float* W1  = (const float*)d_in[3];
  const float* g1  = (const float*)d_in[4];
  const float* b1  = (const float*)d_in[5];
  const float* W2  = (const float*)d_in[6];
  const float* g2  = (const float*)d_in[7];
  const float* b2  = (const float*)d_in[8];
  const float* W3  = (const float*)d_in[9];
  const float* g3  = (const float*)d_in[10];
  const float* b3  = (const float*)d_in[11];

  float* out0     = (float*)d_out;
  float* out_cent = out0 + (size_t)NB*MC*CH3;
  float* out_bsel = out_cent + (size_t)NB*MC*3;

  char* base = (char*)d_ws;
  size_t off = 0;
  auto carve = [&](size_t bytes) -> char* {
    char* p = base + off;
    off = (off + bytes + 255) & ~(size_t)255;
    return p;
  };
  float* centf = (float*)carve(sizeof(float)*NB*MC*3);
  int*   nbr   = (int*)  carve(sizeof(int)*NE);
  int*   cntpc = (int*)  carve(sizeof(int)*NB*MC);
  char*  zeroblk = carve(16 + 512*sizeof(float));
  int*   cnt_total = (int*)zeroblk;
  float* ST = (float*)(zeroblk + 16);
  float *S1 = ST, *Q1 = ST+64, *S2 = ST+128, *Q2 = ST+192, *S3 = ST+256, *Q3 = ST+384;
  float* SC = (float*)carve(512*sizeof(float));
  float *A1 = SC, *B1 = SC+64, *A2 = SC+128, *B2 = SC+192, *A3 = SC+256, *B3 = SC+384;
  u16* y1g = (u16*)carve((size_t)NE*CH1*2);
  u16* y2g = (u16*)carve((size_t)NE*CH2*2);
  size_t needA = off;
  bool planA = (ws_size >= needA);

  hipMemsetAsync(zeroblk, 0, 16 + 512*sizeof(float), stream);
  k_fps<<<NB, 512, 0, stream>>>(pos, centf, out_cent, out_bsel);
  k_ball<<<NB*MC, 256, 0, stream>>>(pos, centf, nbr, cntpc, cnt_total);

  CA ca;
  ca.x = x; ca.pos = pos; ca.centf = centf; ca.nbr = nbr; ca.cntpc = cntpc;
  ca.W1f = W1; ca.W2f = W2; ca.W3f = W3; ca.SC = SC;
  ca.y1g = y1g; ca.y2g = y2g; ca.out0 = out0;

  dim3 sg(NB*MC/4), sb(256);
  if (planA) {
    ca.S = S1; ca.Q = Q1; k_stage<1, true><<<sg, sb, 0, stream>>>(ca);
    k_finalize<<<1, 128, 0, stream>>>(S1, Q1, g1, b1, cnt_total, A1, B1, CH1);
    ca.S = S2; ca.Q = Q2; k_stage<2, true><<<sg, sb, 0, stream>>>(ca);
    k_finalize<<<1, 128, 0, stream>>>(S2, Q2, g2, b2, cnt_total, A2, B2, CH2);
    ca.S = S3; ca.Q = Q3; k_stage<3, true><<<sg, sb, 0, stream>>>(ca);
    k_finalize<<<1, 128, 0, stream>>>(S3, Q3, g3, b3, cnt_total, A3, B3, CH3);
    k_stage<4, true><<<sg, sb, 0, stream>>>(ca);
  } else {
    ca.S = S1; ca.Q = Q1; k_stage<1, false><<<sg, sb, 0, stream>>>(ca);
    k_finalize<<<1, 128, 0, stream>>>(S1, Q1, g1, b1, cnt_total, A1, B1, CH1);
    ca.S = S2; ca.Q = Q2; k_stage<2, false><<<sg, sb, 0, stream>>>(ca);
    k_finalize<<<1, 128, 0, stream>>>(S2, Q2, g2, b2, cnt_total, A2, B2, CH2);
    ca.S = S3; ca.Q = Q3; k_stage<3, false><<<sg, sb, 0, stream>>>(ca);
    k_finalize<<<1, 128, 0, stream>>>(S3, Q3, g3, b3, cnt_total, A3, B3, CH3);
    k_stage<4, false><<<sg, sb, 0, stream>>>(ca);
  }
}

// Round 4
// 2522.452 us; speedup vs baseline: 5.1125x; 5.1125x over previous
//
#include <hip/hip_runtime.h>
#include <stdint.h>

#define NB   8
#define NPTS 4096
#define CINV 64
#define MC   1024
#define KNB  64
#define NE   (NB*MC*KNB)
#define K1   67
#define CH1  64
#define CH2  64
#define CH3  128
#define NSLOT 64   // stats partial shards

typedef unsigned short u16;
typedef unsigned int   u32;
typedef unsigned long long u64;

static __device__ __forceinline__ float bf2f(u16 b){ return __uint_as_float(((u32)b)<<16); }
static __device__ __forceinline__ u16  f2bf(float f){
  u32 u = __float_as_uint(f);
  return (u16)((u + 0x7fffu + ((u>>16)&1u)) >> 16);
}
// Exact replica of reference distance: square each diff, sum as (x+y)+z, NO fma contraction.
static __device__ __forceinline__ float d2ref(float ax,float ay,float az,
                                              float bx,float by,float bz){
  float dx = ax-bx, dy = ay-by, dz = az-bz;
  return __fadd_rn(__fadd_rn(__fmul_rn(dx,dx), __fmul_rn(dy,dy)), __fmul_rn(dz,dz));
}
static __device__ __forceinline__ float wsum(float v){
  #pragma unroll
  for (int off = 32; off > 0; off >>= 1) v += __shfl_xor(v, off);
  return v;
}
static __device__ __forceinline__ float wmax(float v){
  #pragma unroll
  for (int off = 32; off > 0; off >>= 1) v = fmaxf(v, __shfl_xor(v, off));
  return v;
}

// ---------------------------------------------------------------- FPS (unchanged, correctness-verified)
__global__ __launch_bounds__(512) void k_fps(const float* __restrict__ pos,
                                             float* __restrict__ centf,
                                             float* __restrict__ out_cent,
                                             float* __restrict__ out_bsel) {
  __shared__ float px[NPTS], py[NPTS], pz[NPTS];
  __shared__ float redv[8];
  __shared__ int   redi[8];
  __shared__ int   sIdx[MC];
  const int b = blockIdx.x, tid = threadIdx.x;
  for (int i = tid; i < NPTS; i += 512) {
    size_t o = ((size_t)b*NPTS + i)*3;
    px[i] = pos[o]; py[i] = pos[o+1]; pz[i] = pos[o+2];
  }
  if (tid == 0) sIdx[0] = 0;
  __syncthreads();

  float cxr[8], cyr[8], czr[8], dist[8];
  #pragma unroll
  for (int j = 0; j < 8; ++j) {
    int p = tid*8 + j;
    cxr[j] = px[p]; cyr[j] = py[p]; czr[j] = pz[p];
    dist[j] = 1e10f;
  }
  int last = 0;
  const int lane = tid & 63, w = tid >> 6;

  for (int it = 1; it < MC; ++it) {
    const float qx = px[last], qy = py[last], qz = pz[last];
    float bv = -1.f; int bi = 0;
    #pragma unroll
    for (int j = 0; j < 8; ++j) {
      float d  = d2ref(cxr[j], cyr[j], czr[j], qx, qy, qz);
      float nd = fminf(dist[j], d);
      dist[j] = nd;
      if (nd > bv) { bv = nd; bi = tid*8 + j; }   // strict > keeps lowest index
    }
    #pragma unroll
    for (int off = 32; off > 0; off >>= 1) {
      float ov = __shfl_xor(bv, off);
      int   oi = __shfl_xor(bi, off);
      if (ov > bv || (ov == bv && oi < bi)) { bv = ov; bi = oi; }
    }
    if (lane == 0) { redv[w] = bv; redi[w] = bi; }
    __syncthreads();
    bv = redv[0]; bi = redi[0];
    #pragma unroll
    for (int q = 1; q < 8; ++q) {
      float ov = redv[q]; int oi = redi[q];
      if (ov > bv || (ov == bv && oi < bi)) { bv = ov; bi = oi; }
    }
    last = bi;
    if (tid == 0) sIdx[it] = last;
    __syncthreads();
  }

  for (int m = tid; m < MC; m += 512) {
    int i = sIdx[m];
    int r = b*MC + m;
    float qx = px[i], qy = py[i], qz = pz[i];
    centf[r*3+0] = qx; centf[r*3+1] = qy; centf[r*3+2] = qz;
    out_cent[r*3+0] = qx; out_cent[r*3+1] = qy; out_cent[r*3+2] = qz;
    out_bsel[r] = (float)b;
  }
}

// ---------------------------------------------------------------- ball query (unchanged)
#define CAP 2048
__global__ __launch_bounds__(256) void k_ball(const float* __restrict__ pos,
                                              const float* __restrict__ centf,
                                              int* __restrict__ nbr,
                                              int* __restrict__ cntpc,
                                              int* __restrict__ cnt_total) {
  __shared__ u64 keys[CAP];
  __shared__ int scnt;
  const int bm = blockIdx.x, tid = threadIdx.x;
  const int b = bm >> 10;
  if (tid == 0) scnt = 0;
  __syncthreads();
  const float cx = centf[bm*3], cy = centf[bm*3+1], cz = centf[bm*3+2];
  for (int i = tid; i < NPTS; i += 256) {
    size_t o = ((size_t)b*NPTS + i)*3;
    float d = d2ref(cx, cy, cz, pos[o], pos[o+1], pos[o+2]);
    if (d <= 0.04f) {
      int p = atomicAdd(&scnt, 1);
      if (p < CAP) keys[p] = ((u64)__float_as_uint(d) << 32) | (u32)i;
    }
  }
  __syncthreads();
  int n = scnt; if (n > CAP) n = CAP;
  int P = 64; while (P < n) P <<= 1;
  for (int i = n + tid; i < P; i += 256) keys[i] = ~0ull;
  __syncthreads();
  for (int ks = 2; ks <= P; ks <<= 1)
    for (int js = ks >> 1; js > 0; js >>= 1) {
      for (int i = tid; i < P; i += 256) {
        int l = i ^ js;
        if (l > i) {
          u64 a = keys[i], c = keys[l];
          bool up = ((i & ks) == 0);
          if ((a > c) == up) { keys[i] = c; keys[l] = a; }
        }
      }
      __syncthreads();
    }
  int c = n < KNB ? n : KNB;
  if (tid < KNB) nbr[(size_t)bm*KNB + tid] = (tid < c) ? (int)(u32)(keys[tid] & 0xffffffffu) : 0;
  if (tid == 0) { cntpc[bm] = c; atomicAdd(cnt_total, c); }
}

// ---------------------------------------------------------------- stage 1: h=[x_j, pj-ci] @ W1, stats, y1 store
// block = 1 centroid (64 edges), 256 threads = 64 edges x 4 col-groups of 16 ch.
__global__ __launch_bounds__(256) void k_s1(const float* __restrict__ x,
                                            const float* __restrict__ pos,
                                            const float* __restrict__ centf,
                                            const int* __restrict__ nbr,
                                            const int* __restrict__ cntpc,
                                            const float* __restrict__ W1,
                                            float* __restrict__ Spart,
                                            u16* __restrict__ y1g) {
  __shared__ float Hs[64*69];      // pitch 69 (odd) -> conflict-free k-loop reads
  __shared__ float Wsh[K1*CH1];
  __shared__ int   nbrS[64];
  __shared__ float red[4][32];
  __shared__ int   cntS;
  const int tid = threadIdx.x, bm = blockIdx.x;
  const int b = bm >> 10;
  if (tid < 64) nbrS[tid] = nbr[bm*64 + tid];
  if (tid == 0) cntS = cntpc[bm];
  for (int i = tid; i < K1*CH1; i += 256) Wsh[i] = W1[i];
  __syncthreads();
  {
    const int ge = tid >> 2, qb = tid & 3;
    const float4* xr = (const float4*)(x + ((size_t)(b*NPTS + nbrS[ge]))*CINV);
    #pragma unroll
    for (int rep = 0; rep < 4; ++rep) {
      int q = qb + rep*4;
      float4 v = xr[q];
      float* d = Hs + ge*69 + q*4;
      d[0] = v.x; d[1] = v.y; d[2] = v.z; d[3] = v.w;
    }
  }
  if (tid < 64) {
    int row = b*NPTS + nbrS[tid];
    Hs[tid*69+64] = pos[(size_t)row*3+0] - centf[bm*3+0];
    Hs[tid*69+65] = pos[(size_t)row*3+1] - centf[bm*3+1];
    Hs[tid*69+66] = pos[(size_t)row*3+2] - centf[bm*3+2];
  }
  __syncthreads();

  const int edge = tid & 63, col = tid >> 6;
  float acc[16];
  #pragma unroll
  for (int j = 0; j < 16; ++j) acc[j] = 0.f;
  const float* hrow = Hs + edge*69;
  const float* wcol = Wsh + col*16;
  for (int k = 0; k < K1; ++k) {
    float hk = hrow[k];
    const float4* w4 = (const float4*)(wcol + k*CH1);
    #pragma unroll
    for (int q = 0; q < 4; ++q) {
      float4 wv = w4[q];
      acc[q*4+0] = fmaf(hk, wv.x, acc[q*4+0]);
      acc[q*4+1] = fmaf(hk, wv.y, acc[q*4+1]);
      acc[q*4+2] = fmaf(hk, wv.z, acc[q*4+2]);
      acc[q*4+3] = fmaf(hk, wv.w, acc[q*4+3]);
    }
  }
  const bool valid = edge < cntS;
  #pragma unroll
  for (int j = 0; j < 16; ++j) acc[j] = valid ? acc[j] : 0.f;
  // store y1 (masked) as bf16
  u32* dst = (u32*)(y1g + ((size_t)bm*64 + edge)*CH1 + col*16);
  #pragma unroll
  for (int j = 0; j < 8; ++j)
    dst[j] = (u32)f2bf(acc[2*j]) | ((u32)f2bf(acc[2*j+1]) << 16);
  // stats
  #pragma unroll
  for (int j = 0; j < 16; ++j) {
    float s = wsum(acc[j]);
    float q = wsum(acc[j]*acc[j]);
    if (edge == 0) { red[col][j] = s; red[col][16+j] = q; }
  }
  __syncthreads();
  const int slot = bm & (NSLOT-1);
  if (tid < 64)  atomicAdd(&Spart[slot*256 + tid], red[tid>>4][tid&15]);
  else if (tid < 128) {
    int c = tid - 64;
    atomicAdd(&Spart[slot*256 + 128 + c], red[c>>4][16 + (c&15)]);
  }
}

// ---------------------------------------------------------------- stage 2: relu(bn1(y1)) @ W2
__global__ __launch_bounds__(256) void k_s2(const u16* __restrict__ y1g,
                                            const float* __restrict__ SC,
                                            const float* __restrict__ W2,
                                            const int* __restrict__ cntpc,
                                            float* __restrict__ Spart,
                                            u16* __restrict__ y2g) {
  __shared__ float Hs[64*65];
  __shared__ float Wsh[CH1*CH2];
  __shared__ float ABs[128];
  __shared__ float red[4][32];
  __shared__ int   cntS;
  const int tid = threadIdx.x, bm = blockIdx.x;
  if (tid == 0) cntS = cntpc[bm];
  if (tid < 128) ABs[tid] = SC[tid];            // A1(64) B1(64)
  for (int i = tid; i < CH1*CH2; i += 256) Wsh[i] = W2[i];
  __syncthreads();
  {
    const u32* yt = (const u32*)y1g + (size_t)bm*2048;  // 64 edges * 32 u32
    #pragma unroll
    for (int rep = 0; rep < 8; ++rep) {
      int g = rep*256 + tid;
      int e = g >> 5, c2 = g & 31, ch = c2*2;
      u32 v = yt[g];
      float lo = fmaxf(fmaf(bf2f((u16)(v & 0xffff)), ABs[ch],   ABs[64+ch]),   0.f);
      float hi = fmaxf(fmaf(bf2f((u16)(v >> 16)),    ABs[ch+1], ABs[64+ch+1]), 0.f);
      Hs[e*65 + ch] = lo; Hs[e*65 + ch + 1] = hi;
    }
  }
  __syncthreads();

  const int edge = tid & 63, col = tid >> 6;
  float acc[16];
  #pragma unroll
  for (int j = 0; j < 16; ++j) acc[j] = 0.f;
  const float* hrow = Hs + edge*65;
  const float* wcol = Wsh + col*16;
  for (int k = 0; k < CH1; ++k) {
    float hk = hrow[k];
    const float4* w4 = (const float4*)(wcol + k*CH2);
    #pragma unroll
    for (int q = 0; q < 4; ++q) {
      float4 wv = w4[q];
      acc[q*4+0] = fmaf(hk, wv.x, acc[q*4+0]);
      acc[q*4+1] = fmaf(hk, wv.y, acc[q*4+1]);
      acc[q*4+2] = fmaf(hk, wv.z, acc[q*4+2]);
      acc[q*4+3] = fmaf(hk, wv.w, acc[q*4+3]);
    }
  }
  const bool valid = edge < cntS;
  #pragma unroll
  for (int j = 0; j < 16; ++j) acc[j] = valid ? acc[j] : 0.f;
  u32* dst = (u32*)(y2g + ((size_t)bm*64 + edge)*CH2 + col*16);
  #pragma unroll
  for (int j = 0; j < 8; ++j)
    dst[j] = (u32)f2bf(acc[2*j]) | ((u32)f2bf(acc[2*j+1]) << 16);
  #pragma unroll
  for (int j = 0; j < 16; ++j) {
    float s = wsum(acc[j]);
    float q = wsum(acc[j]*acc[j]);
    if (edge == 0) { red[col][j] = s; red[col][16+j] = q; }
  }
  __syncthreads();
  const int slot = bm & (NSLOT-1);
  if (tid < 64)  atomicAdd(&Spart[slot*256 + tid], red[tid>>4][tid&15]);
  else if (tid < 128) {
    int c = tid - 64;
    atomicAdd(&Spart[slot*256 + 128 + c], red[c>>4][16 + (c&15)]);
  }
}

// ---------------------------------------------------------------- stage 3: relu(bn2(y2)) @ W3 (+ optional y3 store / fused bn3+maxpool)
template<bool STORE>
__global__ __launch_bounds__(256) void k_s3(const u16* __restrict__ y2g,
                                            const float* __restrict__ SC,
                                            const float* __restrict__ W3,
                                            const int* __restrict__ cntpc,
                                            float* __restrict__ Spart,
                                            u16* __restrict__ y3g,
                                            float* __restrict__ out0) {
  __shared__ float Hs[64*65];
  __shared__ float Wsh[CH2*CH3];
  __shared__ float ABs[128];
  __shared__ float red[4][64];
  __shared__ int   cntS;
  const int tid = threadIdx.x, bm = blockIdx.x;
  if (tid == 0) cntS = cntpc[bm];
  if (tid < 128) ABs[tid] = SC[128 + tid];      // A2(64) B2(64)
  for (int i = tid; i < CH2*CH3; i += 256) Wsh[i] = W3[i];
  __syncthreads();
  {
    const u32* yt = (const u32*)y2g + (size_t)bm*2048;
    #pragma unroll
    for (int rep = 0; rep < 8; ++rep) {
      int g = rep*256 + tid;
      int e = g >> 5, c2 = g & 31, ch = c2*2;
      u32 v = yt[g];
      float lo = fmaxf(fmaf(bf2f((u16)(v & 0xffff)), ABs[ch],   ABs[64+ch]),   0.f);
      float hi = fmaxf(fmaf(bf2f((u16)(v >> 16)),    ABs[ch+1], ABs[64+ch+1]), 0.f);
      Hs[e*65 + ch] = lo; Hs[e*65 + ch + 1] = hi;
    }
  }
  __syncthreads();

  const int edge = tid & 63, col = tid >> 6;   // col owns 32 of 128 ch
  float acc[32];
  #pragma unroll
  for (int j = 0; j < 32; ++j) acc[j] = 0.f;
  const float* hrow = Hs + edge*65;
  const float* wcol = Wsh + col*32;
  for (int k = 0; k < CH2; ++k) {
    float hk = hrow[k];
    const float4* w4 = (const float4*)(wcol + k*CH3);
    #pragma unroll
    for (int q = 0; q < 8; ++q) {
      float4 wv = w4[q];
      acc[q*4+0] = fmaf(hk, wv.x, acc[q*4+0]);
      acc[q*4+1] = fmaf(hk, wv.y, acc[q*4+1]);
      acc[q*4+2] = fmaf(hk, wv.z, acc[q*4+2]);
      acc[q*4+3] = fmaf(hk, wv.w, acc[q*4+3]);
    }
  }
  const bool valid = edge < cntS;
  #pragma unroll
  for (int j = 0; j < 32; ++j) acc[j] = valid ? acc[j] : 0.f;
  if constexpr (STORE) {
    u32* dst = (u32*)(y3g + ((size_t)bm*64 + edge)*CH3 + col*32);
    #pragma unroll
    for (int j = 0; j < 16; ++j)
      dst[j] = (u32)f2bf(acc[2*j]) | ((u32)f2bf(acc[2*j+1]) << 16);
  }
  #pragma unroll
  for (int j = 0; j < 32; ++j) {
    float s = wsum(acc[j]);
    float q = wsum(acc[j]*acc[j]);
    if (edge == 0) { red[col][j] = s; red[col][32+j] = q; }
  }
  __syncthreads();
  const int slot = bm & (NSLOT-1);
  if (tid < 128) atomicAdd(&Spart[slot*256 + tid], red[tid>>5][tid&31]);
  else {
    int c = tid - 128;
    atomicAdd(&Spart[slot*256 + 128 + c], red[c>>5][32 + (c&31)]);
  }
}

// ---------------------------------------------------------------- stage 4A: bn3+relu+maxpool from stored y3 (memory-bound)
__global__ __launch_bounds__(128) void k_s4(const u16* __restrict__ y3g,
                                            const float* __restrict__ SC,
                                            const int* __restrict__ cntpc,
                                            float* __restrict__ out0) {
  const int tid = threadIdx.x, bm = blockIdx.x;
  const int cnt = cntpc[bm];
  const float a = SC[256 + tid], b = SC[384 + tid];
  const u16* yr = y3g + (size_t)bm*64*CH3 + tid;
  float mx = -1e30f;
  for (int e = 0; e < cnt; ++e) {
    float v = bf2f(yr[e*CH3]);
    mx = fmaxf(mx, fmaxf(fmaf(v, a, b), 0.f));
  }
  out0[(size_t)bm*CH3 + tid] = mx;
}

// ---------------------------------------------------------------- stage 4B (fallback): recompute y3 from y2, fused bn3+maxpool
__global__ __launch_bounds__(256) void k_s4r(const u16* __restrict__ y2g,
                                             const float* __restrict__ SC,
                                             const float* __restrict__ W3,
                                             const int* __restrict__ cntpc,
                                             float* __restrict__ out0) {
  __shared__ float Hs[64*65];
  __shared__ float Wsh[CH2*CH3];
  __shared__ float ABs[128];
  __shared__ float AB3[256];
  __shared__ int   cntS;
  const int tid = threadIdx.x, bm = blockIdx.x;
  if (tid == 0) cntS = cntpc[bm];
  if (tid < 128) ABs[tid] = SC[128 + tid];
  ((float*)AB3)[tid] = SC[256 + tid];   // A3(128) B3(128)
  for (int i = tid; i < CH2*CH3; i += 256) Wsh[i] = W3[i];
  __syncthreads();
  {
    const u32* yt = (const u32*)y2g + (size_t)bm*2048;
    #pragma unroll
    for (int rep = 0; rep < 8; ++rep) {
      int g = rep*256 + tid;
      int e = g >> 5, c2 = g & 31, ch = c2*2;
      u32 v = yt[g];
      float lo = fmaxf(fmaf(bf2f((u16)(v & 0xffff)), ABs[ch],   ABs[64+ch]),   0.f);
      float hi = fmaxf(fmaf(bf2f((u16)(v >> 16)),    ABs[ch+1], ABs[64+ch+1]), 0.f);
      Hs[e*65 + ch] = lo; Hs[e*65 + ch + 1] = hi;
    }
  }
  __syncthreads();
  const int edge = tid & 63, col = tid >> 6;
  float acc[32];
  #pragma unroll
  for (int j = 0; j < 32; ++j) acc[j] = 0.f;
  const float* hrow = Hs + edge*65;
  const float* wcol = Wsh + col*32;
  for (int k = 0; k < CH2; ++k) {
    float hk = hrow[k];
    const float4* w4 = (const float4*)(wcol + k*CH3);
    #pragma unroll
    for (int q = 0; q < 8; ++q) {
      float4 wv = w4[q];
      acc[q*4+0] = fmaf(hk, wv.x, acc[q*4+0]);
      acc[q*4+1] = fmaf(hk, wv.y, acc[q*4+1]);
      acc[q*4+2] = fmaf(hk, wv.z, acc[q*4+2]);
      acc[q*4+3] = fmaf(hk, wv.w, acc[q*4+3]);
    }
  }
  const bool valid = edge < cntS;
  #pragma unroll
  for (int j = 0; j < 32; ++j) {
    int ch = col*32 + j;
    float h = fmaxf(fmaf(acc[j], AB3[ch], AB3[128+ch]), 0.f);
    float mx = wmax(valid ? h : -1e30f);
    if (edge == 0) out0[(size_t)bm*CH3 + ch] = mx;
  }
}

// ---------------------------------------------------------------- finalize: per-stage bn scale/shift from sharded partials
__global__ void k_finalize(const float* __restrict__ Spart,
                           const float* __restrict__ g, const float* __restrict__ bb,
                           const int* __restrict__ cnt_total,
                           float* __restrict__ Aout, float* __restrict__ Bout, int C) {
  int c = threadIdx.x;
  if (c < C) {
    float s = 0.f, q = 0.f;
    for (int sl = 0; sl < NSLOT; ++sl) {
      s += Spart[sl*256 + c];
      q += Spart[sl*256 + 128 + c];
    }
    float n = (float)(*cnt_total); if (n < 1.f) n = 1.f;
    float mu  = s / n;
    float var = q / n - mu*mu; if (var < 0.f) var = 0.f;
    float inv = 1.0f / sqrtf(var + 1e-5f);
    float a = g[c] * inv;
    Aout[c] = a;
    Bout[c] = bb[c] - mu*a;
  }
}

// ---------------------------------------------------------------- host
extern "C" void kernel_launch(void* const* d_in, const int* in_sizes, int n_in,
                              void* d_out, int out_size, void* d_ws, size_t ws_size,
                              hipStream_t stream) {
  (void)in_sizes; (void)n_in; (void)out_size;
  const float* x   = (const float*)d_in[0];
  const float* pos = (const float*)d_in[1];
  const float* W1  = (const float*)d_in[3];
  const float* g1  = (const float*)d_in[4];
  const float* b1  = (const float*)d_in[5];
  const float* W2  = (const float*)d_in[6];
  const float* g2  = (const float*)d_in[7];
  const float* b2  = (const float*)d_in[8];
  const float* W3  = (const float*)d_in[9];
  const float* g3  = (const float*)d_in[10];
  const float* b3  = (const float*)d_in[11];

  float* out0     = (float*)d_out;
  float* out_cent = out0 + (size_t)NB*MC*CH3;
  float* out_bsel = out_cent + (size_t)NB*MC*3;

  char* base = (char*)d_ws;
  size_t off = 0;
  auto carve = [&](size_t bytes) -> char* {
    char* p = base + off;
    off = (off + bytes + 255) & ~(size_t)255;
    return p;
  };
  float* centf = (float*)carve(sizeof(float)*NB*MC*3);
  int*   nbr   = (int*)  carve(sizeof(int)*NE);
  int*   cntpc = (int*)  carve(sizeof(int)*NB*MC);
  // zero region: cnt_total + 3 sharded stat-partial buffers (NSLOT x 256 floats each)
  char*  zeroblk = carve(256 + 3*NSLOT*256*sizeof(float));
  int*   cnt_total = (int*)zeroblk;
  float* Sp1 = (float*)(zeroblk + 256);
  float* Sp2 = Sp1 + NSLOT*256;
  float* Sp3 = Sp2 + NSLOT*256;
  float* SC = (float*)carve(512*sizeof(float));  // A1 B1 A2 B2 A3(128) B3(128)
  u16* y1g = (u16*)carve((size_t)NE*CH1*2);
  u16* y2g = (u16*)carve((size_t)NE*CH2*2);
  size_t base_need = off;
  u16* y3g = (u16*)carve((size_t)NE*CH3*2);
  bool have_y3 = (ws_size >= off);
  bool ok = (ws_size >= base_need);   // round-3 proved this fits; fallback anyway
  (void)ok;

  hipMemsetAsync(zeroblk, 0, 256 + 3*NSLOT*256*sizeof(float), stream);
  k_fps<<<NB, 512, 0, stream>>>(pos, centf, out_cent, out_bsel);
  k_ball<<<NB*MC, 256, 0, stream>>>(pos, centf, nbr, cntpc, cnt_total);

  dim3 sg(NB*MC), sb(256);
  k_s1<<<sg, sb, 0, stream>>>(x, pos, centf, nbr, cntpc, W1, Sp1, y1g);
  k_finalize<<<1, 128, 0, stream>>>(Sp1, g1, b1, cnt_total, SC + 0,   SC + 64,  CH1);
  k_s2<<<sg, sb, 0, stream>>>(y1g, SC, W2, cntpc, Sp2, y2g);
  k_finalize<<<1, 128, 0, stream>>>(Sp2, g2, b2, cnt_total, SC + 128, SC + 192, CH2);
  if (have_y3) {
    k_s3<true><<<sg, sb, 0, stream>>>(y2g, SC, W3, cntpc, Sp3, y3g, out0);
    k_finalize<<<1, 128, 0, stream>>>(Sp3, g3, b3, cnt_total, SC + 256, SC + 384, CH3);
    k_s4<<<sg, 128, 0, stream>>>(y3g, SC, cntpc, out0);
  } else {
    k_s3<false><<<sg, sb, 0, stream>>>(y2g, SC, W3, cntpc, Sp3, y3g, out0);
    k_finalize<<<1, 128, 0, stream>>>(Sp3, g3, b3, cnt_total, SC + 256, SC + 384, CH3);
    k_s4r<<<sg, sb, 0, stream>>>(y2g, SC, W3, cntpc, out0);
  }
}

// Round 5
// 2349.306 us; speedup vs baseline: 5.4893x; 1.0737x over previous
//
#include <hip/hip_runtime.h>
#include <stdint.h>

#define NB   8
#define NPTS 4096
#define CINV 64
#define MC   1024
#define KNB  64
#define NE   (NB*MC*KNB)
#define K1   67
#define CH1  64
#define CH2  64
#define CH3  128
#define NSLOT 64   // stats partial shards

typedef unsigned short u16;
typedef unsigned int   u32;
typedef unsigned long long u64;

static __device__ __forceinline__ float bf2f(u16 b){ return __uint_as_float(((u32)b)<<16); }
static __device__ __forceinline__ u16  f2bf(float f){
  u32 u = __float_as_uint(f);
  return (u16)((u + 0x7fffu + ((u>>16)&1u)) >> 16);
}
// Exact replica of reference distance: square each diff, sum as (x+y)+z, NO fma contraction.
static __device__ __forceinline__ float d2ref(float ax,float ay,float az,
                                              float bx,float by,float bz){
  float dx = ax-bx, dy = ay-by, dz = az-bz;
  return __fadd_rn(__fadd_rn(__fmul_rn(dx,dx), __fmul_rn(dy,dy)), __fmul_rn(dz,dz));
}
static __device__ __forceinline__ float wsum(float v){
  #pragma unroll
  for (int off = 32; off > 0; off >>= 1) v += __shfl_xor(v, off);
  return v;
}
static __device__ __forceinline__ float wmax(float v){
  #pragma unroll
  for (int off = 32; off > 0; off >>= 1) v = fmaxf(v, __shfl_xor(v, off));
  return v;
}

// ---------------------------------------------------------------- FPS v2: latency-optimized serial loop
// One block per cloud. 512 thr x 8 pts. Per iteration: local scan (VALU, tracks
// coords in regs) -> value-only wave max (1 shuffle/step) -> ballot+ffs for
// lowest winning lane (preserves argmax first-max semantics: lanes own
// contiguous ascending index ranges) -> winner publishes (d,idx,x,y,z) ->
// ONE barrier -> every wave resolves 8 candidates in registers (no 2nd barrier;
// double-buffered slots bound skew to 1).
__global__ __launch_bounds__(512) void k_fps(const float* __restrict__ pos,
                                             float* __restrict__ centf,
                                             float* __restrict__ out_cent,
                                             float* __restrict__ out_bsel) {
  __shared__ float px[NPTS], py[NPTS], pz[NPTS];
  __shared__ int   sIdx[MC];
  __shared__ float cD[16]; __shared__ int cI[16];
  __shared__ float cX[16], cY[16], cZ[16];
  const int b = blockIdx.x, tid = threadIdx.x;
  for (int i = tid; i < NPTS; i += 512) {
    size_t o = ((size_t)b*NPTS + i)*3;
    px[i] = pos[o]; py[i] = pos[o+1]; pz[i] = pos[o+2];
  }
  if (tid == 0) sIdx[0] = 0;
  __syncthreads();

  float cxr[8], cyr[8], czr[8], dist[8];
  #pragma unroll
  for (int j = 0; j < 8; ++j) {
    int p = tid*8 + j;
    cxr[j] = px[p]; cyr[j] = py[p]; czr[j] = pz[p];
    dist[j] = 1e10f;
  }
  const int lane = tid & 63, w = tid >> 6;
  float qx = px[0], qy = py[0], qz = pz[0];

  for (int it = 1; it < MC; ++it) {
    float bv = -1.f, bx = 0.f, by = 0.f, bz = 0.f; int bi = 0;
    #pragma unroll
    for (int j = 0; j < 8; ++j) {
      float d  = d2ref(cxr[j], cyr[j], czr[j], qx, qy, qz);
      float nd = fminf(dist[j], d);
      dist[j] = nd;
      if (nd > bv) { bv = nd; bi = tid*8 + j; bx = cxr[j]; by = cyr[j]; bz = czr[j]; }
    }
    // value-only wave max (single f32 op per step)
    float gv = bv;
    #pragma unroll
    for (int off = 32; off > 0; off >>= 1) gv = fmaxf(gv, __shfl_xor(gv, off));
    // lowest lane holding the max == lowest point index (lanes own ascending ranges)
    u64 m = __ballot(bv == gv);
    int wl = __ffsll((unsigned long long)m) - 1;
    const int base = (it & 1) * 8;
    if (lane == wl) {
      cD[base+w] = gv; cI[base+w] = bi;
      cX[base+w] = bx; cY[base+w] = by; cZ[base+w] = bz;
    }
    __syncthreads();
    float bd = cD[base]; int wi = cI[base];
    float nx = cX[base], ny = cY[base], nz = cZ[base];
    #pragma unroll
    for (int q = 1; q < 8; ++q) {
      float dq = cD[base+q];
      bool t = dq > bd;          // strict >: ties keep lower wave (lower index)
      bd = t ? dq : bd;  wi = t ? cI[base+q] : wi;
      nx = t ? cX[base+q] : nx; ny = t ? cY[base+q] : ny; nz = t ? cZ[base+q] : nz;
    }
    qx = nx; qy = ny; qz = nz;
    if (tid == 0) sIdx[it] = wi;
  }
  __syncthreads();

  for (int m2 = tid; m2 < MC; m2 += 512) {
    int i = sIdx[m2];
    int r = b*MC + m2;
    float ox = px[i], oy = py[i], oz = pz[i];
    centf[r*3+0] = ox; centf[r*3+1] = oy; centf[r*3+2] = oz;
    out_cent[r*3+0] = ox; out_cent[r*3+1] = oy; out_cent[r*3+2] = oz;
    out_bsel[r] = (float)b;
  }
}

// ---------------------------------------------------------------- ball query (unchanged)
#define CAP 2048
__global__ __launch_bounds__(256) void k_ball(const float* __restrict__ pos,
                                              const float* __restrict__ centf,
                                              int* __restrict__ nbr,
                                              int* __restrict__ cntpc,
                                              int* __restrict__ cnt_total) {
  __shared__ u64 keys[CAP];
  __shared__ int scnt;
  const int bm = blockIdx.x, tid = threadIdx.x;
  const int b = bm >> 10;
  if (tid == 0) scnt = 0;
  __syncthreads();
  const float cx = centf[bm*3], cy = centf[bm*3+1], cz = centf[bm*3+2];
  for (int i = tid; i < NPTS; i += 256) {
    size_t o = ((size_t)b*NPTS + i)*3;
    float d = d2ref(cx, cy, cz, pos[o], pos[o+1], pos[o+2]);
    if (d <= 0.04f) {
      int p = atomicAdd(&scnt, 1);
      if (p < CAP) keys[p] = ((u64)__float_as_uint(d) << 32) | (u32)i;
    }
  }
  __syncthreads();
  int n = scnt; if (n > CAP) n = CAP;
  int P = 64; while (P < n) P <<= 1;
  for (int i = n + tid; i < P; i += 256) keys[i] = ~0ull;
  __syncthreads();
  for (int ks = 2; ks <= P; ks <<= 1)
    for (int js = ks >> 1; js > 0; js >>= 1) {
      for (int i = tid; i < P; i += 256) {
        int l = i ^ js;
        if (l > i) {
          u64 a = keys[i], c = keys[l];
          bool up = ((i & ks) == 0);
          if ((a > c) == up) { keys[i] = c; keys[l] = a; }
        }
      }
      __syncthreads();
    }
  int c = n < KNB ? n : KNB;
  if (tid < KNB) nbr[(size_t)bm*KNB + tid] = (tid < c) ? (int)(u32)(keys[tid] & 0xffffffffu) : 0;
  if (tid == 0) { cntpc[bm] = c; atomicAdd(cnt_total, c); }
}

// ---------------------------------------------------------------- stage 1: h=[x_j, pj-ci] @ W1, stats, y1 store
__global__ __launch_bounds__(256) void k_s1(const float* __restrict__ x,
                                            const float* __restrict__ pos,
                                            const float* __restrict__ centf,
                                            const int* __restrict__ nbr,
                                            const int* __restrict__ cntpc,
                                            const float* __restrict__ W1,
                                            float* __restrict__ Spart,
                                            u16* __restrict__ y1g) {
  __shared__ float Hs[64*69];      // pitch 69 (odd) -> conflict-free k-loop reads
  __shared__ float Wsh[K1*CH1];
  __shared__ int   nbrS[64];
  __shared__ float red[4][32];
  __shared__ int   cntS;
  const int tid = threadIdx.x, bm = blockIdx.x;
  const int b = bm >> 10;
  if (tid < 64) nbrS[tid] = nbr[bm*64 + tid];
  if (tid == 0) cntS = cntpc[bm];
  for (int i = tid; i < K1*CH1; i += 256) Wsh[i] = W1[i];
  __syncthreads();
  {
    const int ge = tid >> 2, qb = tid & 3;
    const float4* xr = (const float4*)(x + ((size_t)(b*NPTS + nbrS[ge]))*CINV);
    #pragma unroll
    for (int rep = 0; rep < 4; ++rep) {
      int q = qb + rep*4;
      float4 v = xr[q];
      float* d = Hs + ge*69 + q*4;
      d[0] = v.x; d[1] = v.y; d[2] = v.z; d[3] = v.w;
    }
  }
  if (tid < 64) {
    int row = b*NPTS + nbrS[tid];
    Hs[tid*69+64] = pos[(size_t)row*3+0] - centf[bm*3+0];
    Hs[tid*69+65] = pos[(size_t)row*3+1] - centf[bm*3+1];
    Hs[tid*69+66] = pos[(size_t)row*3+2] - centf[bm*3+2];
  }
  __syncthreads();

  const int edge = tid & 63, col = tid >> 6;
  float acc[16];
  #pragma unroll
  for (int j = 0; j < 16; ++j) acc[j] = 0.f;
  const float* hrow = Hs + edge*69;
  const float* wcol = Wsh + col*16;
  for (int k = 0; k < K1; ++k) {
    float hk = hrow[k];
    const float4* w4 = (const float4*)(wcol + k*CH1);
    #pragma unroll
    for (int q = 0; q < 4; ++q) {
      float4 wv = w4[q];
      acc[q*4+0] = fmaf(hk, wv.x, acc[q*4+0]);
      acc[q*4+1] = fmaf(hk, wv.y, acc[q*4+1]);
      acc[q*4+2] = fmaf(hk, wv.z, acc[q*4+2]);
      acc[q*4+3] = fmaf(hk, wv.w, acc[q*4+3]);
    }
  }
  const bool valid = edge < cntS;
  #pragma unroll
  for (int j = 0; j < 16; ++j) acc[j] = valid ? acc[j] : 0.f;
  u32* dst = (u32*)(y1g + ((size_t)bm*64 + edge)*CH1 + col*16);
  #pragma unroll
  for (int j = 0; j < 8; ++j)
    dst[j] = (u32)f2bf(acc[2*j]) | ((u32)f2bf(acc[2*j+1]) << 16);
  #pragma unroll
  for (int j = 0; j < 16; ++j) {
    float s = wsum(acc[j]);
    float q = wsum(acc[j]*acc[j]);
    if (edge == 0) { red[col][j] = s; red[col][16+j] = q; }
  }
  __syncthreads();
  const int slot = bm & (NSLOT-1);
  if (tid < 64)  atomicAdd(&Spart[slot*256 + tid], red[tid>>4][tid&15]);
  else if (tid < 128) {
    int c = tid - 64;
    atomicAdd(&Spart[slot*256 + 128 + c], red[c>>4][16 + (c&15)]);
  }
}

// ---------------------------------------------------------------- stage 2: relu(bn1(y1)) @ W2
__global__ __launch_bounds__(256) void k_s2(const u16* __restrict__ y1g,
                                            const float* __restrict__ SC,
                                            const float* __restrict__ W2,
                                            const int* __restrict__ cntpc,
                                            float* __restrict__ Spart,
                                            u16* __restrict__ y2g) {
  __shared__ float Hs[64*65];
  __shared__ float Wsh[CH1*CH2];
  __shared__ float ABs[128];
  __shared__ float red[4][32];
  __shared__ int   cntS;
  const int tid = threadIdx.x, bm = blockIdx.x;
  if (tid == 0) cntS = cntpc[bm];
  if (tid < 128) ABs[tid] = SC[tid];            // A1(64) B1(64)
  for (int i = tid; i < CH1*CH2; i += 256) Wsh[i] = W2[i];
  __syncthreads();
  {
    const u32* yt = (const u32*)y1g + (size_t)bm*2048;  // 64 edges * 32 u32
    #pragma unroll
    for (int rep = 0; rep < 8; ++rep) {
      int g = rep*256 + tid;
      int e = g >> 5, c2 = g & 31, ch = c2*2;
      u32 v = yt[g];
      float lo = fmaxf(fmaf(bf2f((u16)(v & 0xffff)), ABs[ch],   ABs[64+ch]),   0.f);
      float hi = fmaxf(fmaf(bf2f((u16)(v >> 16)),    ABs[ch+1], ABs[64+ch+1]), 0.f);
      Hs[e*65 + ch] = lo; Hs[e*65 + ch + 1] = hi;
    }
  }
  __syncthreads();

  const int edge = tid & 63, col = tid >> 6;
  float acc[16];
  #pragma unroll
  for (int j = 0; j < 16; ++j) acc[j] = 0.f;
  const float* hrow = Hs + edge*65;
  const float* wcol = Wsh + col*16;
  for (int k = 0; k < CH1; ++k) {
    float hk = hrow[k];
    const float4* w4 = (const float4*)(wcol + k*CH2);
    #pragma unroll
    for (int q = 0; q < 4; ++q) {
      float4 wv = w4[q];
      acc[q*4+0] = fmaf(hk, wv.x, acc[q*4+0]);
      acc[q*4+1] = fmaf(hk, wv.y, acc[q*4+1]);
      acc[q*4+2] = fmaf(hk, wv.z, acc[q*4+2]);
      acc[q*4+3] = fmaf(hk, wv.w, acc[q*4+3]);
    }
  }
  const bool valid = edge < cntS;
  #pragma unroll
  for (int j = 0; j < 16; ++j) acc[j] = valid ? acc[j] : 0.f;
  u32* dst = (u32*)(y2g + ((size_t)bm*64 + edge)*CH2 + col*16);
  #pragma unroll
  for (int j = 0; j < 8; ++j)
    dst[j] = (u32)f2bf(acc[2*j]) | ((u32)f2bf(acc[2*j+1]) << 16);
  #pragma unroll
  for (int j = 0; j < 16; ++j) {
    float s = wsum(acc[j]);
    float q = wsum(acc[j]*acc[j]);
    if (edge == 0) { red[col][j] = s; red[col][16+j] = q; }
  }
  __syncthreads();
  const int slot = bm & (NSLOT-1);
  if (tid < 64)  atomicAdd(&Spart[slot*256 + tid], red[tid>>4][tid&15]);
  else if (tid < 128) {
    int c = tid - 64;
    atomicAdd(&Spart[slot*256 + 128 + c], red[c>>4][16 + (c&15)]);
  }
}

// ---------------------------------------------------------------- stage 3: relu(bn2(y2)) @ W3
template<bool STORE>
__global__ __launch_bounds__(256) void k_s3(const u16* __restrict__ y2g,
                                            const float* __restrict__ SC,
                                            const float* __restrict__ W3,
                                            const int* __restrict__ cntpc,
                                            float* __restrict__ Spart,
                                            u16* __restrict__ y3g,
                                            float* __restrict__ out0) {
  __shared__ float Hs[64*65];
  __shared__ float Wsh[CH2*CH3];
  __shared__ float ABs[128];
  __shared__ float red[4][64];
  __shared__ int   cntS;
  const int tid = threadIdx.x, bm = blockIdx.x;
  if (tid == 0) cntS = cntpc[bm];
  if (tid < 128) ABs[tid] = SC[128 + tid];      // A2(64) B2(64)
  for (int i = tid; i < CH2*CH3; i += 256) Wsh[i] = W3[i];
  __syncthreads();
  {
    const u32* yt = (const u32*)y2g + (size_t)bm*2048;
    #pragma unroll
    for (int rep = 0; rep < 8; ++rep) {
      int g = rep*256 + tid;
      int e = g >> 5, c2 = g & 31, ch = c2*2;
      u32 v = yt[g];
      float lo = fmaxf(fmaf(bf2f((u16)(v & 0xffff)), ABs[ch],   ABs[64+ch]),   0.f);
      float hi = fmaxf(fmaf(bf2f((u16)(v >> 16)),    ABs[ch+1], ABs[64+ch+1]), 0.f);
      Hs[e*65 + ch] = lo; Hs[e*65 + ch + 1] = hi;
    }
  }
  __syncthreads();

  const int edge = tid & 63, col = tid >> 6;   // col owns 32 of 128 ch
  float acc[32];
  #pragma unroll
  for (int j = 0; j < 32; ++j) acc[j] = 0.f;
  const float* hrow = Hs + edge*65;
  const float* wcol = Wsh + col*32;
  for (int k = 0; k < CH2; ++k) {
    float hk = hrow[k];
    const float4* w4 = (const float4*)(wcol + k*CH3);
    #pragma unroll
    for (int q = 0; q < 8; ++q) {
      float4 wv = w4[q];
      acc[q*4+0] = fmaf(hk, wv.x, acc[q*4+0]);
      acc[q*4+1] = fmaf(hk, wv.y, acc[q*4+1]);
      acc[q*4+2] = fmaf(hk, wv.z, acc[q*4+2]);
      acc[q*4+3] = fmaf(hk, wv.w, acc[q*4+3]);
    }
  }
  const bool valid = edge < cntS;
  #pragma unroll
  for (int j = 0; j < 32; ++j) acc[j] = valid ? acc[j] : 0.f;
  if constexpr (STORE) {
    u32* dst = (u32*)(y3g + ((size_t)bm*64 + edge)*CH3 + col*32);
    #pragma unroll
    for (int j = 0; j < 16; ++j)
      dst[j] = (u32)f2bf(acc[2*j]) | ((u32)f2bf(acc[2*j+1]) << 16);
  }
  #pragma unroll
  for (int j = 0; j < 32; ++j) {
    float s = wsum(acc[j]);
    float q = wsum(acc[j]*acc[j]);
    if (edge == 0) { red[col][j] = s; red[col][32+j] = q; }
  }
  __syncthreads();
  const int slot = bm & (NSLOT-1);
  if (tid < 128) atomicAdd(&Spart[slot*256 + tid], red[tid>>5][tid&31]);
  else {
    int c = tid - 128;
    atomicAdd(&Spart[slot*256 + 128 + c], red[c>>5][32 + (c&31)]);
  }
}

// ---------------------------------------------------------------- stage 4A: bn3+relu+maxpool from stored y3
__global__ __launch_bounds__(128) void k_s4(const u16* __restrict__ y3g,
                                            const float* __restrict__ SC,
                                            const int* __restrict__ cntpc,
                                            float* __restrict__ out0) {
  const int tid = threadIdx.x, bm = blockIdx.x;
  const int cnt = cntpc[bm];
  const float a = SC[256 + tid], b = SC[384 + tid];
  const u16* yr = y3g + (size_t)bm*64*CH3 + tid;
  float mx = -1e30f;
  for (int e = 0; e < cnt; ++e) {
    float v = bf2f(yr[e*CH3]);
    mx = fmaxf(mx, fmaxf(fmaf(v, a, b), 0.f));
  }
  out0[(size_t)bm*CH3 + tid] = mx;
}

// ---------------------------------------------------------------- stage 4B (fallback): recompute y3 from y2
__global__ __launch_bounds__(256) void k_s4r(const u16* __restrict__ y2g,
                                             const float* __restrict__ SC,
                                             const float* __restrict__ W3,
                                             const int* __restrict__ cntpc,
                                             float* __restrict__ out0) {
  __shared__ float Hs[64*65];
  __shared__ float Wsh[CH2*CH3];
  __shared__ float ABs[128];
  __shared__ float AB3[256];
  __shared__ int   cntS;
  const int tid = threadIdx.x, bm = blockIdx.x;
  if (tid == 0) cntS = cntpc[bm];
  if (tid < 128) ABs[tid] = SC[128 + tid];
  ((float*)AB3)[tid] = SC[256 + tid];   // A3(128) B3(128)
  for (int i = tid; i < CH2*CH3; i += 256) Wsh[i] = W3[i];
  __syncthreads();
  {
    const u32* yt = (const u32*)y2g + (size_t)bm*2048;
    #pragma unroll
    for (int rep = 0; rep < 8; ++rep) {
      int g = rep*256 + tid;
      int e = g >> 5, c2 = g & 31, ch = c2*2;
      u32 v = yt[g];
      float lo = fmaxf(fmaf(bf2f((u16)(v & 0xffff)), ABs[ch],   ABs[64+ch]),   0.f);
      float hi = fmaxf(fmaf(bf2f((u16)(v >> 16)),    ABs[ch+1], ABs[64+ch+1]), 0.f);
      Hs[e*65 + ch] = lo; Hs[e*65 + ch + 1] = hi;
    }
  }
  __syncthreads();
  const int edge = tid & 63, col = tid >> 6;
  float acc[32];
  #pragma unroll
  for (int j = 0; j < 32; ++j) acc[j] = 0.f;
  const float* hrow = Hs + edge*65;
  const float* wcol = Wsh + col*32;
  for (int k = 0; k < CH2; ++k) {
    float hk = hrow[k];
    const float4* w4 = (const float4*)(wcol + k*CH3);
    #pragma unroll
    for (int q = 0; q < 8; ++q) {
      float4 wv = w4[q];
      acc[q*4+0] = fmaf(hk, wv.x, acc[q*4+0]);
      acc[q*4+1] = fmaf(hk, wv.y, acc[q*4+1]);
      acc[q*4+2] = fmaf(hk, wv.z, acc[q*4+2]);
      acc[q*4+3] = fmaf(hk, wv.w, acc[q*4+3]);
    }
  }
  const bool valid = edge < cntS;
  #pragma unroll
  for (int j = 0; j < 32; ++j) {
    int ch = col*32 + j;
    float h = fmaxf(fmaf(acc[j], AB3[ch], AB3[128+ch]), 0.f);
    float mx = wmax(valid ? h : -1e30f);
    if (edge == 0) out0[(size_t)bm*CH3 + ch] = mx;
  }
}

// ---------------------------------------------------------------- finalize
__global__ void k_finalize(const float* __restrict__ Spart,
                           const float* __restrict__ g, const float* __restrict__ bb,
                           const int* __restrict__ cnt_total,
                           float* __restrict__ Aout, float* __restrict__ Bout, int C) {
  int c = threadIdx.x;
  if (c < C) {
    float s = 0.f, q = 0.f;
    for (int sl = 0; sl < NSLOT; ++sl) {
      s += Spart[sl*256 + c];
      q += Spart[sl*256 + 128 + c];
    }
    float n = (float)(*cnt_total); if (n < 1.f) n = 1.f;
    float mu  = s / n;
    float var = q / n - mu*mu; if (var < 0.f) var = 0.f;
    float inv = 1.0f / sqrtf(var + 1e-5f);
    float a = g[c] * inv;
    Aout[c] = a;
    Bout[c] = bb[c] - mu*a;
  }
}

// ---------------------------------------------------------------- host
extern "C" void kernel_launch(void* const* d_in, const int* in_sizes, int n_in,
                              void* d_out, int out_size, void* d_ws, size_t ws_size,
                              hipStream_t stream) {
  (void)in_sizes; (void)n_in; (void)out_size;
  const float* x   = (const float*)d_in[0];
  const float* pos = (const float*)d_in[1];
  const float* W1  = (const float*)d_in[3];
  const float* g1  = (const float*)d_in[4];
  const float* b1  = (const float*)d_in[5];
  const float* W2  = (const float*)d_in[6];
  const float* g2  = (const float*)d_in[7];
  const float* b2  = (const float*)d_in[8];
  const float* W3  = (const float*)d_in[9];
  const float* g3  = (const float*)d_in[10];
  const float* b3  = (const float*)d_in[11];

  float* out0     = (float*)d_out;
  float* out_cent = out0 + (size_t)NB*MC*CH3;
  float* out_bsel = out_cent + (size_t)NB*MC*3;

  char* base = (char*)d_ws;
  size_t off = 0;
  auto carve = [&](size_t bytes) -> char* {
    char* p = base + off;
    off = (off + bytes + 255) & ~(size_t)255;
    return p;
  };
  float* centf = (float*)carve(sizeof(float)*NB*MC*3);
  int*   nbr   = (int*)  carve(sizeof(int)*NE);
  int*   cntpc = (int*)  carve(sizeof(int)*NB*MC);
  char*  zeroblk = carve(256 + 3*NSLOT*256*sizeof(float));
  int*   cnt_total = (int*)zeroblk;
  float* Sp1 = (float*)(zeroblk + 256);
  float* Sp2 = Sp1 + NSLOT*256;
  float* Sp3 = Sp2 + NSLOT*256;
  float* SC = (float*)carve(512*sizeof(float));  // A1 B1 A2 B2 A3(128) B3(128)
  u16* y1g = (u16*)carve((size_t)NE*CH1*2);
  u16* y2g = (u16*)carve((size_t)NE*CH2*2);
  u16* y3g = (u16*)carve((size_t)NE*CH3*2);
  bool have_y3 = (ws_size >= off);

  hipMemsetAsync(zeroblk, 0, 256 + 3*NSLOT*256*sizeof(float), stream);
  k_fps<<<NB, 512, 0, stream>>>(pos, centf, out_cent, out_bsel);
  k_ball<<<NB*MC, 256, 0, stream>>>(pos, centf, nbr, cntpc, cnt_total);

  dim3 sg(NB*MC), sb(256);
  k_s1<<<sg, sb, 0, stream>>>(x, pos, centf, nbr, cntpc, W1, Sp1, y1g);
  k_finalize<<<1, 128, 0, stream>>>(Sp1, g1, b1, cnt_total, SC + 0,   SC + 64,  CH1);
  k_s2<<<sg, sb, 0, stream>>>(y1g, SC, W2, cntpc, Sp2, y2g);
  k_finalize<<<1, 128, 0, stream>>>(Sp2, g2, b2, cnt_total, SC + 128, SC + 192, CH2);
  if (have_y3) {
    k_s3<true><<<sg, sb, 0, stream>>>(y2g, SC, W3, cntpc, Sp3, y3g, out0);
    k_finalize<<<1, 128, 0, stream>>>(Sp3, g3, b3, cnt_total, SC + 256, SC + 384, CH3);
    k_s4<<<sg, 128, 0, stream>>>(y3g, SC, cntpc, out0);
  } else {
    k_s3<false><<<sg, sb, 0, stream>>>(y2g, SC, W3, cntpc, Sp3, y3g, out0);
    k_finalize<<<1, 128, 0, stream>>>(Sp3, g3, b3, cnt_total, SC + 256, SC + 384, CH3);
    k_s4r<<<sg, sb, 0, stream>>>(y2g, SC, W3, cntpc, out0);
  }
}

// Round 6
// 2119.412 us; speedup vs baseline: 6.0847x; 1.1085x over previous
//
#include <hip/hip_runtime.h>
#include <stdint.h>

#define NB   8
#define NPTS 4096
#define CINV 64
#define MC   1024
#define KNB  64
#define NE   (NB*MC*KNB)
#define K1   67
#define CH1  64
#define CH2  64
#define CH3  128
#define NSLOT 64
#define CAP  2048
#define NTASK (NB*MC)
#define NBLK 128      // 8 FPS + 120 workers; <= worst-case residency (256 @ 1 blk/CU)

typedef unsigned short u16;
typedef unsigned int   u32;
typedef unsigned long long u64;

static __device__ __forceinline__ float bf2f(u16 b){ return __uint_as_float(((u32)b)<<16); }
static __device__ __forceinline__ u16  f2bf(float f){
  u32 u = __float_as_uint(f);
  return (u16)((u + 0x7fffu + ((u>>16)&1u)) >> 16);
}
// Exact replica of reference distance: square each diff, sum as (x+y)+z, NO fma contraction.
static __device__ __forceinline__ float d2ref(float ax,float ay,float az,
                                              float bx,float by,float bz){
  float dx = ax-bx, dy = ay-by, dz = az-bz;
  return __fadd_rn(__fadd_rn(__fmul_rn(dx,dx), __fmul_rn(dy,dy)), __fmul_rn(dz,dz));
}
static __device__ __forceinline__ float wsum(float v){
  #pragma unroll
  for (int off = 32; off > 0; off >>= 1) v += __shfl_xor(v, off);
  return v;
}
static __device__ __forceinline__ float wmax(float v){
  #pragma unroll
  for (int off = 32; off > 0; off >>= 1) v = fmaxf(v, __shfl_xor(v, off));
  return v;
}

// ---------------------------------------------------------------- fused front kernel
struct FpsL {
  float px[NPTS], py[NPTS], pz[NPTS];
  float cD[16]; int cI[16];
  float cX[16], cY[16], cZ[16];
};
struct WkL {
  u64   keys[CAP];        // ball-query sort keys
  float Wsh[K1*CH1];      // W1, loaded once per block
  float Hs[64*69];        // stage-1 H tile (odd pitch)
  int   nbrS[64];
  float red[8][16];
  float cxyz[3];
  int   scnt;
  int   task;
};
union FrontL { FpsL f; WkL w; };

__global__ __launch_bounds__(512) void k_front(const float* __restrict__ x,
                                               const float* __restrict__ pos,
                                               float* __restrict__ centf,
                                               float* __restrict__ out_cent,
                                               float* __restrict__ out_bsel,
                                               const float* __restrict__ W1,
                                               float* __restrict__ Spart,
                                               u16* __restrict__ y1g,
                                               int* __restrict__ cntpc,
                                               int* __restrict__ cnt_total,
                                               int* __restrict__ progress,
                                               int* __restrict__ taskctr) {
  __shared__ FrontL L;
  const int tid = threadIdx.x;

  if (blockIdx.x < NB) {
    // =========================== FPS producer (round-5 math, progressive publish)
    const int b = blockIdx.x;
    for (int i = tid; i < NPTS; i += 512) {
      size_t o = ((size_t)b*NPTS + i)*3;
      L.f.px[i] = pos[o]; L.f.py[i] = pos[o+1]; L.f.pz[i] = pos[o+2];
    }
    __syncthreads();

    float cxr[8], cyr[8], czr[8], dist[8];
    #pragma unroll
    for (int j = 0; j < 8; ++j) {
      int p = tid*8 + j;
      cxr[j] = L.f.px[p]; cyr[j] = L.f.py[p]; czr[j] = L.f.pz[p];
      dist[j] = 1e10f;
    }
    const int lane = tid & 63, w = tid >> 6;
    float qx = L.f.px[0], qy = L.f.py[0], qz = L.f.pz[0];
    if (tid == 0) {
      int r = b*MC;
      centf[r*3+0]=qx; centf[r*3+1]=qy; centf[r*3+2]=qz;
      out_cent[r*3+0]=qx; out_cent[r*3+1]=qy; out_cent[r*3+2]=qz;
      out_bsel[r] = (float)b;
    }

    for (int it = 1; it < MC; ++it) {
      float bv = -1.f, bx = 0.f, by = 0.f, bz = 0.f; int bi = 0;
      #pragma unroll
      for (int j = 0; j < 8; ++j) {
        float d  = d2ref(cxr[j], cyr[j], czr[j], qx, qy, qz);
        float nd = fminf(dist[j], d);
        dist[j] = nd;
        if (nd > bv) { bv = nd; bi = tid*8 + j; bx = cxr[j]; by = cyr[j]; bz = czr[j]; }
      }
      float gv = bv;
      #pragma unroll
      for (int off = 32; off > 0; off >>= 1) gv = fmaxf(gv, __shfl_xor(gv, off));
      u64 m = __ballot(bv == gv);
      int wl = __ffsll((unsigned long long)m) - 1;
      const int base = (it & 1) * 8;
      if (lane == wl) {
        L.f.cD[base+w] = gv; L.f.cI[base+w] = bi;
        L.f.cX[base+w] = bx; L.f.cY[base+w] = by; L.f.cZ[base+w] = bz;
      }
      __syncthreads();
      float bd = L.f.cD[base]; int wi = L.f.cI[base];
      float nx = L.f.cX[base], ny = L.f.cY[base], nz = L.f.cZ[base];
      #pragma unroll
      for (int q = 1; q < 8; ++q) {
        float dq = L.f.cD[base+q];
        bool t = dq > bd;          // strict >: ties keep lower wave (lower index)
        bd = t ? dq : bd;  wi = t ? L.f.cI[base+q] : wi;
        nx = t ? L.f.cX[base+q] : nx; ny = t ? L.f.cY[base+q] : ny; nz = t ? L.f.cZ[base+q] : nz;
      }
      (void)wi;
      qx = nx; qy = ny; qz = nz;
      if (tid == 0) {
        int r = b*MC + it;
        centf[r*3+0]=nx; centf[r*3+1]=ny; centf[r*3+2]=nz;
        out_cent[r*3+0]=nx; out_cent[r*3+1]=ny; out_cent[r*3+2]=nz;
        out_bsel[r] = (float)b;
        if ((it & 15) == 15)
          __hip_atomic_store(progress + b, it + 1, __ATOMIC_RELEASE, __HIP_MEMORY_SCOPE_AGENT);
      }
    }
    return;
  }

  // =========================== persistent workers: ball query + stage-1 per centroid
  for (int i = tid; i < K1*CH1; i += 512) L.w.Wsh[i] = W1[i];

  for (;;) {
    if (tid == 0) {
      int t = atomicAdd(taskctr, 1);
      L.w.task = t;
      if (t < NTASK) {
        int m = t >> 3, b = t & 7;
        while (__hip_atomic_load(progress + b, __ATOMIC_ACQUIRE, __HIP_MEMORY_SCOPE_AGENT) < m + 1)
          __builtin_amdgcn_s_sleep(8);
        int bm = b*MC + m;
        L.w.cxyz[0] = __hip_atomic_load(centf + bm*3 + 0, __ATOMIC_RELAXED, __HIP_MEMORY_SCOPE_AGENT);
        L.w.cxyz[1] = __hip_atomic_load(centf + bm*3 + 1, __ATOMIC_RELAXED, __HIP_MEMORY_SCOPE_AGENT);
        L.w.cxyz[2] = __hip_atomic_load(centf + bm*3 + 2, __ATOMIC_RELAXED, __HIP_MEMORY_SCOPE_AGENT);
      }
      L.w.scnt = 0;
    }
    __syncthreads();
    const int t = L.w.task;
    if (t >= NTASK) return;
    const int m = t >> 3, b = t & 7, bm = b*MC + m;
    const float cx = L.w.cxyz[0], cy = L.w.cxyz[1], cz = L.w.cxyz[2];

    // ---- ball query (exact ref semantics)
    for (int i = tid; i < NPTS; i += 512) {
      size_t o = ((size_t)b*NPTS + i)*3;
      float d = d2ref(cx, cy, cz, pos[o], pos[o+1], pos[o+2]);
      if (d <= 0.04f) {
        int p = atomicAdd(&L.w.scnt, 1);
        if (p < CAP) L.w.keys[p] = ((u64)__float_as_uint(d) << 32) | (u32)i;
      }
    }
    __syncthreads();
    int n = L.w.scnt; if (n > CAP) n = CAP;
    int P = 64; while (P < n) P <<= 1;
    for (int i = n + tid; i < P; i += 512) L.w.keys[i] = ~0ull;
    __syncthreads();
    for (int ks = 2; ks <= P; ks <<= 1)
      for (int js = ks >> 1; js > 0; js >>= 1) {
        for (int i = tid; i < P; i += 512) {
          int l = i ^ js;
          if (l > i) {
            u64 a = L.w.keys[i], c = L.w.keys[l];
            bool up = ((i & ks) == 0);
            if ((a > c) == up) { L.w.keys[i] = c; L.w.keys[l] = a; }
          }
        }
        __syncthreads();
      }
    const int c = n < KNB ? n : KNB;
    if (tid < KNB) L.w.nbrS[tid] = (tid < c) ? (int)(u32)(L.w.keys[tid] & 0xffffffffu) : 0;
    if (tid == 0) { cntpc[bm] = c; atomicAdd(cnt_total, c); }
    __syncthreads();

    // ---- stage-1: H = [x_j, p_j - c_i] (64x67) staged in LDS
    {
      const int ge = tid >> 3, qb = tid & 7;
      const float4* xr = (const float4*)(x + ((size_t)(b*NPTS + L.w.nbrS[ge]))*CINV);
      #pragma unroll
      for (int rep = 0; rep < 2; ++rep) {
        int q = qb + rep*8;
        float4 v = xr[q];
        float* d = L.w.Hs + ge*69 + q*4;
        d[0] = v.x; d[1] = v.y; d[2] = v.z; d[3] = v.w;
      }
    }
    if (tid < 64) {
      int row = b*NPTS + L.w.nbrS[tid];
      L.w.Hs[tid*69+64] = pos[(size_t)row*3+0] - cx;
      L.w.Hs[tid*69+65] = pos[(size_t)row*3+1] - cy;
      L.w.Hs[tid*69+66] = pos[(size_t)row*3+2] - cz;
    }
    __syncthreads();

    // ---- GEMM: thread = (edge, col of 8 channels); 512 thr = 64 x 8
    const int edge = tid & 63, col = tid >> 6;
    float acc[8];
    #pragma unroll
    for (int j = 0; j < 8; ++j) acc[j] = 0.f;
    const float* hrow = L.w.Hs + edge*69;
    const float* wcol = L.w.Wsh + col*8;
    for (int k = 0; k < K1; ++k) {
      float hk = hrow[k];
      const float4* w4 = (const float4*)(wcol + k*CH1);
      float4 a = w4[0], bq = w4[1];
      acc[0] = fmaf(hk, a.x,  acc[0]); acc[1] = fmaf(hk, a.y,  acc[1]);
      acc[2] = fmaf(hk, a.z,  acc[2]); acc[3] = fmaf(hk, a.w,  acc[3]);
      acc[4] = fmaf(hk, bq.x, acc[4]); acc[5] = fmaf(hk, bq.y, acc[5]);
      acc[6] = fmaf(hk, bq.z, acc[6]); acc[7] = fmaf(hk, bq.w, acc[7]);
    }
    const bool valid = edge < c;
    #pragma unroll
    for (int j = 0; j < 8; ++j) acc[j] = valid ? acc[j] : 0.f;
    u32* dst = (u32*)(y1g + ((size_t)bm*64 + edge)*CH1 + col*8);
    #pragma unroll
    for (int j = 0; j < 4; ++j)
      dst[j] = (u32)f2bf(acc[2*j]) | ((u32)f2bf(acc[2*j+1]) << 16);
    #pragma unroll
    for (int j = 0; j < 8; ++j) {
      float s = wsum(acc[j]);
      float q = wsum(acc[j]*acc[j]);
      if (edge == 0) { L.w.red[col][j] = s; L.w.red[col][8+j] = q; }
    }
    __syncthreads();
    const int slot = bm & (NSLOT-1);
    if (tid < 64)  atomicAdd(&Spart[slot*256 + tid], L.w.red[tid>>3][tid&7]);
    else if (tid < 128) {
      int cc = tid - 64;
      atomicAdd(&Spart[slot*256 + 128 + cc], L.w.red[cc>>3][8 + (cc&7)]);
    }
    // top-of-loop __syncthreads() isolates this task's LDS reads from the next task's writes
  }
}

// ---------------------------------------------------------------- stage 2: relu(bn1(y1)) @ W2
__global__ __launch_bounds__(256) void k_s2(const u16* __restrict__ y1g,
                                            const float* __restrict__ SC,
                                            const float* __restrict__ W2,
                                            const int* __restrict__ cntpc,
                                            float* __restrict__ Spart,
                                            u16* __restrict__ y2g) {
  __shared__ float Hs[64*65];
  __shared__ float Wsh[CH1*CH2];
  __shared__ float ABs[128];
  __shared__ float red[4][32];
  __shared__ int   cntS;
  const int tid = threadIdx.x, bm = blockIdx.x;
  if (tid == 0) cntS = cntpc[bm];
  if (tid < 128) ABs[tid] = SC[tid];            // A1(64) B1(64)
  for (int i = tid; i < CH1*CH2; i += 256) Wsh[i] = W2[i];
  __syncthreads();
  {
    const u32* yt = (const u32*)y1g + (size_t)bm*2048;  // 64 edges * 32 u32
    #pragma unroll
    for (int rep = 0; rep < 8; ++rep) {
      int g = rep*256 + tid;
      int e = g >> 5, c2 = g & 31, ch = c2*2;
      u32 v = yt[g];
      float lo = fmaxf(fmaf(bf2f((u16)(v & 0xffff)), ABs[ch],   ABs[64+ch]),   0.f);
      float hi = fmaxf(fmaf(bf2f((u16)(v >> 16)),    ABs[ch+1], ABs[64+ch+1]), 0.f);
      Hs[e*65 + ch] = lo; Hs[e*65 + ch + 1] = hi;
    }
  }
  __syncthreads();

  const int edge = tid & 63, col = tid >> 6;
  float acc[16];
  #pragma unroll
  for (int j = 0; j < 16; ++j) acc[j] = 0.f;
  const float* hrow = Hs + edge*65;
  const float* wcol = Wsh + col*16;
  for (int k = 0; k < CH1; ++k) {
    float hk = hrow[k];
    const float4* w4 = (const float4*)(wcol + k*CH2);
    #pragma unroll
    for (int q = 0; q < 4; ++q) {
      float4 wv = w4[q];
      acc[q*4+0] = fmaf(hk, wv.x, acc[q*4+0]);
      acc[q*4+1] = fmaf(hk, wv.y, acc[q*4+1]);
      acc[q*4+2] = fmaf(hk, wv.z, acc[q*4+2]);
      acc[q*4+3] = fmaf(hk, wv.w, acc[q*4+3]);
    }
  }
  const bool valid = edge < cntS;
  #pragma unroll
  for (int j = 0; j < 16; ++j) acc[j] = valid ? acc[j] : 0.f;
  u32* dst = (u32*)(y2g + ((size_t)bm*64 + edge)*CH2 + col*16);
  #pragma unroll
  for (int j = 0; j < 8; ++j)
    dst[j] = (u32)f2bf(acc[2*j]) | ((u32)f2bf(acc[2*j+1]) << 16);
  #pragma unroll
  for (int j = 0; j < 16; ++j) {
    float s = wsum(acc[j]);
    float q = wsum(acc[j]*acc[j]);
    if (edge == 0) { red[col][j] = s; red[col][16+j] = q; }
  }
  __syncthreads();
  const int slot = bm & (NSLOT-1);
  if (tid < 64)  atomicAdd(&Spart[slot*256 + tid], red[tid>>4][tid&15]);
  else if (tid < 128) {
    int c = tid - 64;
    atomicAdd(&Spart[slot*256 + 128 + c], red[c>>4][16 + (c&15)]);
  }
}

// ---------------------------------------------------------------- stage 3: relu(bn2(y2)) @ W3
template<bool STORE>
__global__ __launch_bounds__(256) void k_s3(const u16* __restrict__ y2g,
                                            const float* __restrict__ SC,
                                            const float* __restrict__ W3,
                                            const int* __restrict__ cntpc,
                                            float* __restrict__ Spart,
                                            u16* __restrict__ y3g,
                                            float* __restrict__ out0) {
  __shared__ float Hs[64*65];
  __shared__ float Wsh[CH2*CH3];
  __shared__ float ABs[128];
  __shared__ float red[4][64];
  __shared__ int   cntS;
  const int tid = threadIdx.x, bm = blockIdx.x;
  if (tid == 0) cntS = cntpc[bm];
  if (tid < 128) ABs[tid] = SC[128 + tid];      // A2(64) B2(64)
  for (int i = tid; i < CH2*CH3; i += 256) Wsh[i] = W3[i];
  __syncthreads();
  {
    const u32* yt = (const u32*)y2g + (size_t)bm*2048;
    #pragma unroll
    for (int rep = 0; rep < 8; ++rep) {
      int g = rep*256 + tid;
      int e = g >> 5, c2 = g & 31, ch = c2*2;
      u32 v = yt[g];
      float lo = fmaxf(fmaf(bf2f((u16)(v & 0xffff)), ABs[ch],   ABs[64+ch]),   0.f);
      float hi = fmaxf(fmaf(bf2f((u16)(v >> 16)),    ABs[ch+1], ABs[64+ch+1]), 0.f);
      Hs[e*65 + ch] = lo; Hs[e*65 + ch + 1] = hi;
    }
  }
  __syncthreads();

  const int edge = tid & 63, col = tid >> 6;   // col owns 32 of 128 ch
  float acc[32];
  #pragma unroll
  for (int j = 0; j < 32; ++j) acc[j] = 0.f;
  const float* hrow = Hs + edge*65;
  const float* wcol = Wsh + col*32;
  for (int k = 0; k < CH2; ++k) {
    float hk = hrow[k];
    const float4* w4 = (const float4*)(wcol + k*CH3);
    #pragma unroll
    for (int q = 0; q < 8; ++q) {
      float4 wv = w4[q];
      acc[q*4+0] = fmaf(hk, wv.x, acc[q*4+0]);
      acc[q*4+1] = fmaf(hk, wv.y, acc[q*4+1]);
      acc[q*4+2] = fmaf(hk, wv.z, acc[q*4+2]);
      acc[q*4+3] = fmaf(hk, wv.w, acc[q*4+3]);
    }
  }
  const bool valid = edge < cntS;
  #pragma unroll
  for (int j = 0; j < 32; ++j) acc[j] = valid ? acc[j] : 0.f;
  if constexpr (STORE) {
    u32* dst = (u32*)(y3g + ((size_t)bm*64 + edge)*CH3 + col*32);
    #pragma unroll
    for (int j = 0; j < 16; ++j)
      dst[j] = (u32)f2bf(acc[2*j]) | ((u32)f2bf(acc[2*j+1]) << 16);
  }
  #pragma unroll
  for (int j = 0; j < 32; ++j) {
    float s = wsum(acc[j]);
    float q = wsum(acc[j]*acc[j]);
    if (edge == 0) { red[col][j] = s; red[col][32+j] = q; }
  }
  __syncthreads();
  const int slot = bm & (NSLOT-1);
  if (tid < 128) atomicAdd(&Spart[slot*256 + tid], red[tid>>5][tid&31]);
  else {
    int c = tid - 128;
    atomicAdd(&Spart[slot*256 + 128 + c], red[c>>5][32 + (c&31)]);
  }
}

// ---------------------------------------------------------------- stage 4A: bn3+relu+maxpool from stored y3
__global__ __launch_bounds__(128) void k_s4(const u16* __restrict__ y3g,
                                            const float* __restrict__ SC,
                                            const int* __restrict__ cntpc,
                                            float* __restrict__ out0) {
  const int tid = threadIdx.x, bm = blockIdx.x;
  const int cnt = cntpc[bm];
  const float a = SC[256 + tid], b = SC[384 + tid];
  const u16* yr = y3g + (size_t)bm*64*CH3 + tid;
  float mx = -1e30f;
  for (int e = 0; e < cnt; ++e) {
    float v = bf2f(yr[e*CH3]);
    mx = fmaxf(mx, fmaxf(fmaf(v, a, b), 0.f));
  }
  out0[(size_t)bm*CH3 + tid] = mx;
}

// ---------------------------------------------------------------- stage 4B (fallback): recompute y3 from y2
__global__ __launch_bounds__(256) void k_s4r(const u16* __restrict__ y2g,
                                             const float* __restrict__ SC,
                                             const float* __restrict__ W3,
                                             const int* __restrict__ cntpc,
                                             float* __restrict__ out0) {
  __shared__ float Hs[64*65];
  __shared__ float Wsh[CH2*CH3];
  __shared__ float ABs[128];
  __shared__ float AB3[256];
  __shared__ int   cntS;
  const int tid = threadIdx.x, bm = blockIdx.x;
  if (tid == 0) cntS = cntpc[bm];
  if (tid < 128) ABs[tid] = SC[128 + tid];
  ((float*)AB3)[tid] = SC[256 + tid];   // A3(128) B3(128)
  for (int i = tid; i < CH2*CH3; i += 256) Wsh[i] = W3[i];
  __syncthreads();
  {
    const u32* yt = (const u32*)y2g + (size_t)bm*2048;
    #pragma unroll
    for (int rep = 0; rep < 8; ++rep) {
      int g = rep*256 + tid;
      int e = g >> 5, c2 = g & 31, ch = c2*2;
      u32 v = yt[g];
      float lo = fmaxf(fmaf(bf2f((u16)(v & 0xffff)), ABs[ch],   ABs[64+ch]),   0.f);
      float hi = fmaxf(fmaf(bf2f((u16)(v >> 16)),    ABs[ch+1], ABs[64+ch+1]), 0.f);
      Hs[e*65 + ch] = lo; Hs[e*65 + ch + 1] = hi;
    }
  }
  __syncthreads();
  const int edge = tid & 63, col = tid >> 6;
  float acc[32];
  #pragma unroll
  for (int j = 0; j < 32; ++j) acc[j] = 0.f;
  const float* hrow = Hs + edge*65;
  const float* wcol = Wsh + col*32;
  for (int k = 0; k < CH2; ++k) {
    float hk = hrow[k];
    const float4* w4 = (const float4*)(wcol + k*CH3);
    #pragma unroll
    for (int q = 0; q < 8; ++q) {
      float4 wv = w4[q];
      acc[q*4+0] = fmaf(hk, wv.x, acc[q*4+0]);
      acc[q*4+1] = fmaf(hk, wv.y, acc[q*4+1]);
      acc[q*4+2] = fmaf(hk, wv.z, acc[q*4+2]);
      acc[q*4+3] = fmaf(hk, wv.w, acc[q*4+3]);
    }
  }
  const bool valid = edge < cntS;
  #pragma unroll
  for (int j = 0; j < 32; ++j) {
    int ch = col*32 + j;
    float h = fmaxf(fmaf(acc[j], AB3[ch], AB3[128+ch]), 0.f);
    float mx = wmax(valid ? h : -1e30f);
    if (edge == 0) out0[(size_t)bm*CH3 + ch] = mx;
  }
}

// ---------------------------------------------------------------- finalize
__global__ void k_finalize(const float* __restrict__ Spart,
                           const float* __restrict__ g, const float* __restrict__ bb,
                           const int* __restrict__ cnt_total,
                           float* __restrict__ Aout, float* __restrict__ Bout, int C) {
  int c = threadIdx.x;
  if (c < C) {
    float s = 0.f, q = 0.f;
    for (int sl = 0; sl < NSLOT; ++sl) {
      s += Spart[sl*256 + c];
      q += Spart[sl*256 + 128 + c];
    }
    float n = (float)(*cnt_total); if (n < 1.f) n = 1.f;
    float mu  = s / n;
    float var = q / n - mu*mu; if (var < 0.f) var = 0.f;
    float inv = 1.0f / sqrtf(var + 1e-5f);
    float a = g[c] * inv;
    Aout[c] = a;
    Bout[c] = bb[c] - mu*a;
  }
}

// ---------------------------------------------------------------- host
extern "C" void kernel_launch(void* const* d_in, const int* in_sizes, int n_in,
                              void* d_out, int out_size, void* d_ws, size_t ws_size,
                              hipStream_t stream) {
  (void)in_sizes; (void)n_in; (void)out_size;
  const float* x   = (const float*)d_in[0];
  const float* pos = (const float*)d_in[1];
  const float* W1  = (const float*)d_in[3];
  const float* g1  = (const float*)d_in[4];
  const float* b1  = (const float*)d_in[5];
  const float* W2  = (const float*)d_in[6];
  const float* g2  = (const float*)d_in[7];
  const float* b2  = (const float*)d_in[8];
  const float* W3  = (const float*)d_in[9];
  const float* g3  = (const float*)d_in[10];
  const float* b3  = (const float*)d_in[11];

  float* out0     = (float*)d_out;
  float* out_cent = out0 + (size_t)NB*MC*CH3;
  float* out_bsel = out_cent + (size_t)NB*MC*3;

  char* base = (char*)d_ws;
  size_t off = 0;
  auto carve = [&](size_t bytes) -> char* {
    char* p = base + off;
    off = (off + bytes + 255) & ~(size_t)255;
    return p;
  };
  float* centf = (float*)carve(sizeof(float)*NB*MC*3);
  int*   cntpc = (int*)  carve(sizeof(int)*NB*MC);
  char*  zeroblk = carve(256 + 3*NSLOT*256*sizeof(float));
  int*   cnt_total = (int*)zeroblk;
  int*   taskctr   = cnt_total + 1;
  int*   progress  = cnt_total + 2;    // 8 ints
  float* Sp1 = (float*)(zeroblk + 256);
  float* Sp2 = Sp1 + NSLOT*256;
  float* Sp3 = Sp2 + NSLOT*256;
  float* SC = (float*)carve(512*sizeof(float));  // A1 B1 A2 B2 A3(128) B3(128)
  u16* y1g = (u16*)carve((size_t)NE*CH1*2);
  u16* y2g = (u16*)carve((size_t)NE*CH2*2);
  u16* y3g = (u16*)carve((size_t)NE*CH3*2);
  bool have_y3 = (ws_size >= off);

  hipMemsetAsync(zeroblk, 0, 256 + 3*NSLOT*256*sizeof(float), stream);
  k_front<<<NBLK, 512, 0, stream>>>(x, pos, centf, out_cent, out_bsel,
                                    W1, Sp1, y1g, cntpc, cnt_total, progress, taskctr);
  k_finalize<<<1, 128, 0, stream>>>(Sp1, g1, b1, cnt_total, SC + 0,   SC + 64,  CH1);
  dim3 sg(NB*MC), sb(256);
  k_s2<<<sg, sb, 0, stream>>>(y1g, SC, W2, cntpc, Sp2, y2g);
  k_finalize<<<1, 128, 0, stream>>>(Sp2, g2, b2, cnt_total, SC + 128, SC + 192, CH2);
  if (have_y3) {
    k_s3<true><<<sg, sb, 0, stream>>>(y2g, SC, W3, cntpc, Sp3, y3g, out0);
    k_finalize<<<1, 128, 0, stream>>>(Sp3, g3, b3, cnt_total, SC + 256, SC + 384, CH3);
    k_s4<<<sg, 128, 0, stream>>>(y3g, SC, cntpc, out0);
  } else {
    k_s3<false><<<sg, sb, 0, stream>>>(y2g, SC, W3, cntpc, Sp3, y3g, out0);
    k_finalize<<<1, 128, 0, stream>>>(Sp3, g3, b3, cnt_total, SC + 256, SC + 384, CH3);
    k_s4r<<<sg, sb, 0, stream>>>(y2g, SC, W3, cntpc, out0);
  }
}

// Round 7
// 1678.682 us; speedup vs baseline: 7.6822x; 1.2625x over previous
//
#include <hip/hip_runtime.h>
#include <stdint.h>

#define NB   8
#define NPTS 4096
#define CINV 64
#define MC   1024
#define KNB  64
#define NE   (NB*MC*KNB)
#define K1   67
#define CH1  64
#define CH2  64
#define CH3  128
#define NSLOT 64
#define CAP  2048
#define NTASK (NB*MC)
#define NBLK 256      // 8 FPS + 248 workers; LDS ~52.7KB -> >=1 block/CU guaranteed resident

typedef unsigned short u16;
typedef unsigned int   u32;
typedef unsigned long long u64;

static __device__ __forceinline__ float bf2f(u16 b){ return __uint_as_float(((u32)b)<<16); }
static __device__ __forceinline__ u16  f2bf(float f){
  u32 u = __float_as_uint(f);
  return (u16)((u + 0x7fffu + ((u>>16)&1u)) >> 16);
}
// Exact replica of reference distance: square each diff, sum as (x+y)+z, NO fma contraction.
static __device__ __forceinline__ float d2ref(float ax,float ay,float az,
                                              float bx,float by,float bz){
  float dx = ax-bx, dy = ay-by, dz = az-bz;
  return __fadd_rn(__fadd_rn(__fmul_rn(dx,dx), __fmul_rn(dy,dy)), __fmul_rn(dz,dz));
}
static __device__ __forceinline__ float wsum(float v){
  #pragma unroll
  for (int off = 32; off > 0; off >>= 1) v += __shfl_xor(v, off);
  return v;
}
static __device__ __forceinline__ float wmax(float v){
  #pragma unroll
  for (int off = 32; off > 0; off >>= 1) v = fmaxf(v, __shfl_xor(v, off));
  return v;
}
// One DPP max step: v = max(v, dpp_shuffle(v)). Pure VALU (no DS pipe).
template<int CTRL, int RMASK>
static __device__ __forceinline__ float dppmaxstep(float v){
  int t = __builtin_amdgcn_update_dpp(__float_as_int(v), __float_as_int(v),
                                      CTRL, RMASK, 0xF, false);
  return fmaxf(v, __int_as_float(t));
}
// Full wave64 max -> broadcast via readlane(63). Steps: xor1,xor2,half_mirror,mirror,bcast15,bcast31.
static __device__ __forceinline__ float wavemax_dpp(float v){
  v = dppmaxstep<0xB1, 0xF>(v);
  v = dppmaxstep<0x4E, 0xF>(v);
  v = dppmaxstep<0x141,0xF>(v);
  v = dppmaxstep<0x140,0xF>(v);
  v = dppmaxstep<0x142,0xA>(v);
  v = dppmaxstep<0x143,0xC>(v);
  return __int_as_float(__builtin_amdgcn_readlane(__float_as_int(v), 63));
}

// ---------------------------------------------------------------- fused front kernel
struct FpsL {
  float px[NPTS], py[NPTS], pz[NPTS];
  int   sIdx[MC];
  float4 cand[16];   // (d, x, y, z), double-buffered 2x8
  int    cIv[16];
  float4 nxt[2];
  int    nxtI[2];
};
struct WkL {
  u64   keys[CAP];        // ball-query sort keys
  float Wsh[K1*CH1];      // W1, loaded once per block
  float Hs[64*69];        // stage-1 H tile (odd pitch)
  int   nbrS[64];
  float red[8][16];
  float cxyz[3];
  int   scnt;
  int   task;
};
union FrontL { FpsL f; WkL w; };

__global__ __launch_bounds__(512) void k_front(const float* __restrict__ x,
                                               const float* __restrict__ pos,
                                               float* __restrict__ centf,
                                               float* __restrict__ out_cent,
                                               float* __restrict__ out_bsel,
                                               const float* __restrict__ W1,
                                               float* __restrict__ Spart,
                                               u16* __restrict__ y1g,
                                               int* __restrict__ cntpc,
                                               int* __restrict__ cnt_total,
                                               int* __restrict__ progress,
                                               int* __restrict__ taskctr) {
  __shared__ FrontL L;
  const int tid = threadIdx.x;

  if (blockIdx.x < NB) {
    // =========================== FPS producer (DPP reduce, wave0 resolve)
    const int b = blockIdx.x;
    for (int i = tid; i < NPTS; i += 512) {
      size_t o = ((size_t)b*NPTS + i)*3;
      L.f.px[i] = pos[o]; L.f.py[i] = pos[o+1]; L.f.pz[i] = pos[o+2];
    }
    if (tid == 0) L.f.sIdx[0] = 0;
    __syncthreads();

    float cxr[8], cyr[8], czr[8], dist[8];
    #pragma unroll
    for (int j = 0; j < 8; ++j) {
      int p = tid*8 + j;
      cxr[j] = L.f.px[p]; cyr[j] = L.f.py[p]; czr[j] = L.f.pz[p];
      dist[j] = 1e10f;
    }
    const int lane = tid & 63, w = tid >> 6;
    float qx = L.f.px[0], qy = L.f.py[0], qz = L.f.pz[0];
    if (tid == 0) {
      int r = b*MC;
      centf[r*3+0]=qx; centf[r*3+1]=qy; centf[r*3+2]=qz;
    }

    for (int it = 1; it < MC; ++it) {
      float bv = -1.f, bx = 0.f, by = 0.f, bz = 0.f; int bi = 0;
      #pragma unroll
      for (int j = 0; j < 8; ++j) {
        float d  = d2ref(cxr[j], cyr[j], czr[j], qx, qy, qz);
        float nd = fminf(dist[j], d);
        dist[j] = nd;
        if (nd > bv) { bv = nd; bi = tid*8 + j; bx = cxr[j]; by = cyr[j]; bz = czr[j]; }
      }
      // wave max via DPP (VALU only), then lowest winning lane = lowest index
      float gmax = wavemax_dpp(bv);
      u64 mm = __ballot(bv == gmax);
      int wl = __ffsll((unsigned long long)mm) - 1;
      const int base = (it & 1) * 8;
      if (lane == wl) {
        L.f.cand[base + w] = make_float4(gmax, bx, by, bz);
        L.f.cIv[base + w]  = bi;
      }
      __syncthreads();
      if (w == 0) {
        // wave 0 resolves the 8 per-wave candidates: 1 b128 read/lane + 3 DPP steps
        float4 cq = L.f.cand[base + (lane & 7)];
        int    ci = L.f.cIv[base + (lane & 7)];
        float dm = cq.x;
        dm = dppmaxstep<0xB1, 0xF>(dm);
        dm = dppmaxstep<0x4E, 0xF>(dm);
        dm = dppmaxstep<0x141,0xF>(dm);   // all lanes in each 8-group now hold max of 8
        u64 m2 = __ballot(cq.x == dm);
        int wl2 = __ffsll((unsigned long long)m2) - 1;  // lowest lane -> lowest wave -> lowest index
        if (lane == wl2) {
          L.f.nxt[it & 1]  = cq;
          L.f.nxtI[it & 1] = ci;
        }
      }
      __syncthreads();
      float4 nq = L.f.nxt[it & 1];
      qx = nq.y; qy = nq.z; qz = nq.w;
      if (tid == 0) {
        int r = b*MC + it;
        centf[r*3+0]=qx; centf[r*3+1]=qy; centf[r*3+2]=qz;
        L.f.sIdx[it] = L.f.nxtI[it & 1];
        if ((it & 15) == 15)
          __hip_atomic_store(progress + b, it + 1, __ATOMIC_RELEASE, __HIP_MEMORY_SCOPE_AGENT);
      }
    }
    __syncthreads();
    // epilogue: out_cent / out_bsel from sIdx (off the per-iteration critical path)
    for (int m2 = tid; m2 < MC; m2 += 512) {
      int i = L.f.sIdx[m2];
      int r = b*MC + m2;
      out_cent[r*3+0] = L.f.px[i]; out_cent[r*3+1] = L.f.py[i]; out_cent[r*3+2] = L.f.pz[i];
      out_bsel[r] = (float)b;
    }
    return;
  }

  // =========================== persistent workers: ball query + stage-1 per centroid
  for (int i = tid; i < K1*CH1; i += 512) L.w.Wsh[i] = W1[i];

  for (;;) {
    if (tid == 0) {
      int t = atomicAdd(taskctr, 1);
      L.w.task = t;
      if (t < NTASK) {
        int m = t >> 3, b = t & 7;
        while (__hip_atomic_load(progress + b, __ATOMIC_ACQUIRE, __HIP_MEMORY_SCOPE_AGENT) < m + 1)
          __builtin_amdgcn_s_sleep(8);
        int bm = b*MC + m;
        L.w.cxyz[0] = __hip_atomic_load(centf + bm*3 + 0, __ATOMIC_RELAXED, __HIP_MEMORY_SCOPE_AGENT);
        L.w.cxyz[1] = __hip_atomic_load(centf + bm*3 + 1, __ATOMIC_RELAXED, __HIP_MEMORY_SCOPE_AGENT);
        L.w.cxyz[2] = __hip_atomic_load(centf + bm*3 + 2, __ATOMIC_RELAXED, __HIP_MEMORY_SCOPE_AGENT);
      }
      L.w.scnt = 0;
    }
    __syncthreads();
    const int t = L.w.task;
    if (t >= NTASK) return;
    const int m = t >> 3, b = t & 7, bm = b*MC + m;
    const float cx = L.w.cxyz[0], cy = L.w.cxyz[1], cz = L.w.cxyz[2];

    // ---- ball query (exact ref semantics)
    for (int i = tid; i < NPTS; i += 512) {
      size_t o = ((size_t)b*NPTS + i)*3;
      float d = d2ref(cx, cy, cz, pos[o], pos[o+1], pos[o+2]);
      if (d <= 0.04f) {
        int p = atomicAdd(&L.w.scnt, 1);
        if (p < CAP) L.w.keys[p] = ((u64)__float_as_uint(d) << 32) | (u32)i;
      }
    }
    __syncthreads();
    int n = L.w.scnt; if (n > CAP) n = CAP;
    int P = 64; while (P < n) P <<= 1;
    for (int i = n + tid; i < P; i += 512) L.w.keys[i] = ~0ull;
    __syncthreads();
    for (int ks = 2; ks <= P; ks <<= 1)
      for (int js = ks >> 1; js > 0; js >>= 1) {
        for (int i = tid; i < P; i += 512) {
          int l = i ^ js;
          if (l > i) {
            u64 a = L.w.keys[i], c = L.w.keys[l];
            bool up = ((i & ks) == 0);
            if ((a > c) == up) { L.w.keys[i] = c; L.w.keys[l] = a; }
          }
        }
        __syncthreads();
      }
    const int c = n < KNB ? n : KNB;
    if (tid < KNB) L.w.nbrS[tid] = (tid < c) ? (int)(u32)(L.w.keys[tid] & 0xffffffffu) : 0;
    if (tid == 0) { cntpc[bm] = c; atomicAdd(cnt_total, c); }
    __syncthreads();

    // ---- stage-1: H = [x_j, p_j - c_i] (64x67) staged in LDS
    {
      const int ge = tid >> 3, qb = tid & 7;
      const float4* xr = (const float4*)(x + ((size_t)(b*NPTS + L.w.nbrS[ge]))*CINV);
      #pragma unroll
      for (int rep = 0; rep < 2; ++rep) {
        int q = qb + rep*8;
        float4 v = xr[q];
        float* d = L.w.Hs + ge*69 + q*4;
        d[0] = v.x; d[1] = v.y; d[2] = v.z; d[3] = v.w;
      }
    }
    if (tid < 64) {
      int row = b*NPTS + L.w.nbrS[tid];
      L.w.Hs[tid*69+64] = pos[(size_t)row*3+0] - cx;
      L.w.Hs[tid*69+65] = pos[(size_t)row*3+1] - cy;
      L.w.Hs[tid*69+66] = pos[(size_t)row*3+2] - cz;
    }
    __syncthreads();

    // ---- GEMM: thread = (edge, col of 8 channels); 512 thr = 64 x 8
    const int edge = tid & 63, col = tid >> 6;
    float acc[8];
    #pragma unroll
    for (int j = 0; j < 8; ++j) acc[j] = 0.f;
    const float* hrow = L.w.Hs + edge*69;
    const float* wcol = L.w.Wsh + col*8;
    for (int k = 0; k < K1; ++k) {
      float hk = hrow[k];
      const float4* w4 = (const float4*)(wcol + k*CH1);
      float4 a = w4[0], bq = w4[1];
      acc[0] = fmaf(hk, a.x,  acc[0]); acc[1] = fmaf(hk, a.y,  acc[1]);
      acc[2] = fmaf(hk, a.z,  acc[2]); acc[3] = fmaf(hk, a.w,  acc[3]);
      acc[4] = fmaf(hk, bq.x, acc[4]); acc[5] = fmaf(hk, bq.y, acc[5]);
      acc[6] = fmaf(hk, bq.z, acc[6]); acc[7] = fmaf(hk, bq.w, acc[7]);
    }
    const bool valid = edge < c;
    #pragma unroll
    for (int j = 0; j < 8; ++j) acc[j] = valid ? acc[j] : 0.f;
    u32* dst = (u32*)(y1g + ((size_t)bm*64 + edge)*CH1 + col*8);
    #pragma unroll
    for (int j = 0; j < 4; ++j)
      dst[j] = (u32)f2bf(acc[2*j]) | ((u32)f2bf(acc[2*j+1]) << 16);
    #pragma unroll
    for (int j = 0; j < 8; ++j) {
      float s = wsum(acc[j]);
      float q = wsum(acc[j]*acc[j]);
      if (edge == 0) { L.w.red[col][j] = s; L.w.red[col][8+j] = q; }
    }
    __syncthreads();
    const int slot = bm & (NSLOT-1);
    if (tid < 64)  atomicAdd(&Spart[slot*256 + tid], L.w.red[tid>>3][tid&7]);
    else if (tid < 128) {
      int cc = tid - 64;
      atomicAdd(&Spart[slot*256 + 128 + cc], L.w.red[cc>>3][8 + (cc&7)]);
    }
    // top-of-loop __syncthreads() isolates this task's LDS reads from the next task's writes
  }
}

// ---------------------------------------------------------------- stage 2: relu(bn1(y1)) @ W2
__global__ __launch_bounds__(256) void k_s2(const u16* __restrict__ y1g,
                                            const float* __restrict__ SC,
                                            const float* __restrict__ W2,
                                            const int* __restrict__ cntpc,
                                            float* __restrict__ Spart,
                                            u16* __restrict__ y2g) {
  __shared__ float Hs[64*65];
  __shared__ float Wsh[CH1*CH2];
  __shared__ float ABs[128];
  __shared__ float red[4][32];
  __shared__ int   cntS;
  const int tid = threadIdx.x, bm = blockIdx.x;
  if (tid == 0) cntS = cntpc[bm];
  if (tid < 128) ABs[tid] = SC[tid];            // A1(64) B1(64)
  for (int i = tid; i < CH1*CH2; i += 256) Wsh[i] = W2[i];
  __syncthreads();
  {
    const u32* yt = (const u32*)y1g + (size_t)bm*2048;  // 64 edges * 32 u32
    #pragma unroll
    for (int rep = 0; rep < 8; ++rep) {
      int g = rep*256 + tid;
      int e = g >> 5, c2 = g & 31, ch = c2*2;
      u32 v = yt[g];
      float lo = fmaxf(fmaf(bf2f((u16)(v & 0xffff)), ABs[ch],   ABs[64+ch]),   0.f);
      float hi = fmaxf(fmaf(bf2f((u16)(v >> 16)),    ABs[ch+1], ABs[64+ch+1]), 0.f);
      Hs[e*65 + ch] = lo; Hs[e*65 + ch + 1] = hi;
    }
  }
  __syncthreads();

  const int edge = tid & 63, col = tid >> 6;
  float acc[16];
  #pragma unroll
  for (int j = 0; j < 16; ++j) acc[j] = 0.f;
  const float* hrow = Hs + edge*65;
  const float* wcol = Wsh + col*16;
  for (int k = 0; k < CH1; ++k) {
    float hk = hrow[k];
    const float4* w4 = (const float4*)(wcol + k*CH2);
    #pragma unroll
    for (int q = 0; q < 4; ++q) {
      float4 wv = w4[q];
      acc[q*4+0] = fmaf(hk, wv.x, acc[q*4+0]);
      acc[q*4+1] = fmaf(hk, wv.y, acc[q*4+1]);
      acc[q*4+2] = fmaf(hk, wv.z, acc[q*4+2]);
      acc[q*4+3] = fmaf(hk, wv.w, acc[q*4+3]);
    }
  }
  const bool valid = edge < cntS;
  #pragma unroll
  for (int j = 0; j < 16; ++j) acc[j] = valid ? acc[j] : 0.f;
  u32* dst = (u32*)(y2g + ((size_t)bm*64 + edge)*CH2 + col*16);
  #pragma unroll
  for (int j = 0; j < 8; ++j)
    dst[j] = (u32)f2bf(acc[2*j]) | ((u32)f2bf(acc[2*j+1]) << 16);
  #pragma unroll
  for (int j = 0; j < 16; ++j) {
    float s = wsum(acc[j]);
    float q = wsum(acc[j]*acc[j]);
    if (edge == 0) { red[col][j] = s; red[col][16+j] = q; }
  }
  __syncthreads();
  const int slot = bm & (NSLOT-1);
  if (tid < 64)  atomicAdd(&Spart[slot*256 + tid], red[tid>>4][tid&15]);
  else if (tid < 128) {
    int c = tid - 64;
    atomicAdd(&Spart[slot*256 + 128 + c], red[c>>4][16 + (c&15)]);
  }
}

// ---------------------------------------------------------------- stage 3: relu(bn2(y2)) @ W3
template<bool STORE>
__global__ __launch_bounds__(256) void k_s3(const u16* __restrict__ y2g,
                                            const float* __restrict__ SC,
                                            const float* __restrict__ W3,
                                            const int* __restrict__ cntpc,
                                            float* __restrict__ Spart,
                                            u16* __restrict__ y3g,
                                            float* __restrict__ out0) {
  __shared__ float Hs[64*65];
  __shared__ float Wsh[CH2*CH3];
  __shared__ float ABs[128];
  __shared__ float red[4][64];
  __shared__ int   cntS;
  const int tid = threadIdx.x, bm = blockIdx.x;
  if (tid == 0) cntS = cntpc[bm];
  if (tid < 128) ABs[tid] = SC[128 + tid];      // A2(64) B2(64)
  for (int i = tid; i < CH2*CH3; i += 256) Wsh[i] = W3[i];
  __syncthreads();
  {
    const u32* yt = (const u32*)y2g + (size_t)bm*2048;
    #pragma unroll
    for (int rep = 0; rep < 8; ++rep) {
      int g = rep*256 + tid;
      int e = g >> 5, c2 = g & 31, ch = c2*2;
      u32 v = yt[g];
      float lo = fmaxf(fmaf(bf2f((u16)(v & 0xffff)), ABs[ch],   ABs[64+ch]),   0.f);
      float hi = fmaxf(fmaf(bf2f((u16)(v >> 16)),    ABs[ch+1], ABs[64+ch+1]), 0.f);
      Hs[e*65 + ch] = lo; Hs[e*65 + ch + 1] = hi;
    }
  }
  __syncthreads();

  const int edge = tid & 63, col = tid >> 6;   // col owns 32 of 128 ch
  float acc[32];
  #pragma unroll
  for (int j = 0; j < 32; ++j) acc[j] = 0.f;
  const float* hrow = Hs + edge*65;
  const float* wcol = Wsh + col*32;
  for (int k = 0; k < CH2; ++k) {
    float hk = hrow[k];
    const float4* w4 = (const float4*)(wcol + k*CH3);
    #pragma unroll
    for (int q = 0; q < 8; ++q) {
      float4 wv = w4[q];
      acc[q*4+0] = fmaf(hk, wv.x, acc[q*4+0]);
      acc[q*4+1] = fmaf(hk, wv.y, acc[q*4+1]);
      acc[q*4+2] = fmaf(hk, wv.z, acc[q*4+2]);
      acc[q*4+3] = fmaf(hk, wv.w, acc[q*4+3]);
    }
  }
  const bool valid = edge < cntS;
  #pragma unroll
  for (int j = 0; j < 32; ++j) acc[j] = valid ? acc[j] : 0.f;
  if constexpr (STORE) {
    u32* dst = (u32*)(y3g + ((size_t)bm*64 + edge)*CH3 + col*32);
    #pragma unroll
    for (int j = 0; j < 16; ++j)
      dst[j] = (u32)f2bf(acc[2*j]) | ((u32)f2bf(acc[2*j+1]) << 16);
  }
  #pragma unroll
  for (int j = 0; j < 32; ++j) {
    float s = wsum(acc[j]);
    float q = wsum(acc[j]*acc[j]);
    if (edge == 0) { red[col][j] = s; red[col][32+j] = q; }
  }
  __syncthreads();
  const int slot = bm & (NSLOT-1);
  if (tid < 128) atomicAdd(&Spart[slot*256 + tid], red[tid>>5][tid&31]);
  else {
    int c = tid - 128;
    atomicAdd(&Spart[slot*256 + 128 + c], red[c>>5][32 + (c&31)]);
  }
}

// ---------------------------------------------------------------- stage 4A: bn3+relu+maxpool from stored y3
__global__ __launch_bounds__(128) void k_s4(const u16* __restrict__ y3g,
                                            const float* __restrict__ SC,
                                            const int* __restrict__ cntpc,
                                            float* __restrict__ out0) {
  const int tid = threadIdx.x, bm = blockIdx.x;
  const int cnt = cntpc[bm];
  const float a = SC[256 + tid], b = SC[384 + tid];
  const u16* yr = y3g + (size_t)bm*64*CH3 + tid;
  float mx = -1e30f;
  for (int e = 0; e < cnt; ++e) {
    float v = bf2f(yr[e*CH3]);
    mx = fmaxf(mx, fmaxf(fmaf(v, a, b), 0.f));
  }
  out0[(size_t)bm*CH3 + tid] = mx;
}

// ---------------------------------------------------------------- stage 4B (fallback): recompute y3 from y2
__global__ __launch_bounds__(256) void k_s4r(const u16* __restrict__ y2g,
                                             const float* __restrict__ SC,
                                             const float* __restrict__ W3,
                                             const int* __restrict__ cntpc,
                                             float* __restrict__ out0) {
  __shared__ float Hs[64*65];
  __shared__ float Wsh[CH2*CH3];
  __shared__ float ABs[128];
  __shared__ float AB3[256];
  __shared__ int   cntS;
  const int tid = threadIdx.x, bm = blockIdx.x;
  if (tid == 0) cntS = cntpc[bm];
  if (tid < 128) ABs[tid] = SC[128 + tid];
  ((float*)AB3)[tid] = SC[256 + tid];   // A3(128) B3(128)
  for (int i = tid; i < CH2*CH3; i += 256) Wsh[i] = W3[i];
  __syncthreads();
  {
    const u32* yt = (const u32*)y2g + (size_t)bm*2048;
    #pragma unroll
    for (int rep = 0; rep < 8; ++rep) {
      int g = rep*256 + tid;
      int e = g >> 5, c2 = g & 31, ch = c2*2;
      u32 v = yt[g];
      float lo = fmaxf(fmaf(bf2f((u16)(v & 0xffff)), ABs[ch],   ABs[64+ch]),   0.f);
      float hi = fmaxf(fmaf(bf2f((u16)(v >> 16)),    ABs[ch+1], ABs[64+ch+1]), 0.f);
      Hs[e*65 + ch] = lo; Hs[e*65 + ch + 1] = hi;
    }
  }
  __syncthreads();
  const int edge = tid & 63, col = tid >> 6;
  float acc[32];
  #pragma unroll
  for (int j = 0; j < 32; ++j) acc[j] = 0.f;
  const float* hrow = Hs + edge*65;
  const float* wcol = Wsh + col*32;
  for (int k = 0; k < CH2; ++k) {
    float hk = hrow[k];
    const float4* w4 = (const float4*)(wcol + k*CH3);
    #pragma unroll
    for (int q = 0; q < 8; ++q) {
      float4 wv = w4[q];
      acc[q*4+0] = fmaf(hk, wv.x, acc[q*4+0]);
      acc[q*4+1] = fmaf(hk, wv.y, acc[q*4+1]);
      acc[q*4+2] = fmaf(hk, wv.z, acc[q*4+2]);
      acc[q*4+3] = fmaf(hk, wv.w, acc[q*4+3]);
    }
  }
  const bool valid = edge < cntS;
  #pragma unroll
  for (int j = 0; j < 32; ++j) {
    int ch = col*32 + j;
    float h = fmaxf(fmaf(acc[j], AB3[ch], AB3[128+ch]), 0.f);
    float mx = wmax(valid ? h : -1e30f);
    if (edge == 0) out0[(size_t)bm*CH3 + ch] = mx;
  }
}

// ---------------------------------------------------------------- finalize
__global__ void k_finalize(const float* __restrict__ Spart,
                           const float* __restrict__ g, const float* __restrict__ bb,
                           const int* __restrict__ cnt_total,
                           float* __restrict__ Aout, float* __restrict__ Bout, int C) {
  int c = threadIdx.x;
  if (c < C) {
    float s = 0.f, q = 0.f;
    for (int sl = 0; sl < NSLOT; ++sl) {
      s += Spart[sl*256 + c];
      q += Spart[sl*256 + 128 + c];
    }
    float n = (float)(*cnt_total); if (n < 1.f) n = 1.f;
    float mu  = s / n;
    float var = q / n - mu*mu; if (var < 0.f) var = 0.f;
    float inv = 1.0f / sqrtf(var + 1e-5f);
    float a = g[c] * inv;
    Aout[c] = a;
    Bout[c] = bb[c] - mu*a;
  }
}

// ---------------------------------------------------------------- host
extern "C" void kernel_launch(void* const* d_in, const int* in_sizes, int n_in,
                              void* d_out, int out_size, void* d_ws, size_t ws_size,
                              hipStream_t stream) {
  (void)in_sizes; (void)n_in; (void)out_size;
  const float* x   = (const float*)d_in[0];
  const float* pos = (const float*)d_in[1];
  const float* W1  = (const float*)d_in[3];
  const float* g1  = (const float*)d_in[4];
  const float* b1  = (const float*)d_in[5];
  const float* W2  = (const float*)d_in[6];
  const float* g2  = (const float*)d_in[7];
  const float* b2  = (const float*)d_in[8];
  const float* W3  = (const float*)d_in[9];
  const float* g3  = (const float*)d_in[10];
  const float* b3  = (const float*)d_in[11];

  float* out0     = (float*)d_out;
  float* out_cent = out0 + (size_t)NB*MC*CH3;
  float* out_bsel = out_cent + (size_t)NB*MC*3;

  char* base = (char*)d_ws;
  size_t off = 0;
  auto carve = [&](size_t bytes) -> char* {
    char* p = base + off;
    off = (off + bytes + 255) & ~(size_t)255;
    return p;
  };
  float* centf = (float*)carve(sizeof(float)*NB*MC*3);
  int*   cntpc = (int*)  carve(sizeof(int)*NB*MC);
  char*  zeroblk = carve(256 + 3*NSLOT*256*sizeof(float));
  int*   cnt_total = (int*)zeroblk;
  int*   taskctr   = cnt_total + 1;
  int*   progress  = cnt_total + 2;    // 8 ints
  float* Sp1 = (float*)(zeroblk + 256);
  float* Sp2 = Sp1 + NSLOT*256;
  float* Sp3 = Sp2 + NSLOT*256;
  float* SC = (float*)carve(512*sizeof(float));  // A1 B1 A2 B2 A3(128) B3(128)
  u16* y1g = (u16*)carve((size_t)NE*CH1*2);
  u16* y2g = (u16*)carve((size_t)NE*CH2*2);
  u16* y3g = (u16*)carve((size_t)NE*CH3*2);
  bool have_y3 = (ws_size >= off);

  hipMemsetAsync(zeroblk, 0, 256 + 3*NSLOT*256*sizeof(float), stream);
  k_front<<<NBLK, 512, 0, stream>>>(x, pos, centf, out_cent, out_bsel,
                                    W1, Sp1, y1g, cntpc, cnt_total, progress, taskctr);
  k_finalize<<<1, 128, 0, stream>>>(Sp1, g1, b1, cnt_total, SC + 0,   SC + 64,  CH1);
  dim3 sg(NB*MC), sb(256);
  k_s2<<<sg, sb, 0, stream>>>(y1g, SC, W2, cntpc, Sp2, y2g);
  k_finalize<<<1, 128, 0, stream>>>(Sp2, g2, b2, cnt_total, SC + 128, SC + 192, CH2);
  if (have_y3) {
    k_s3<true><<<sg, sb, 0, stream>>>(y2g, SC, W3, cntpc, Sp3, y3g, out0);
    k_finalize<<<1, 128, 0, stream>>>(Sp3, g3, b3, cnt_total, SC + 256, SC + 384, CH3);
    k_s4<<<sg, 128, 0, stream>>>(y3g, SC, cntpc, out0);
  } else {
    k_s3<false><<<sg, sb, 0, stream>>>(y2g, SC, W3, cntpc, Sp3, y3g, out0);
    k_finalize<<<1, 128, 0, stream>>>(Sp3, g3, b3, cnt_total, SC + 256, SC + 384, CH3);
    k_s4r<<<sg, sb, 0, stream>>>(y2g, SC, W3, cntpc, out0);
  }
}

// Round 8
// 1513.452 us; speedup vs baseline: 8.5209x; 1.1092x over previous
//
#include <hip/hip_runtime.h>
#include <stdint.h>

#define NB   8
#define NPTS 4096
#define CINV 64
#define MC   1024
#define KNB  64
#define NE   (NB*MC*KNB)
#define K1   67
#define CH1  64
#define CH2  64
#define CH3  128
#define NSLOT 64
#define CAP  2048
#define NTASK (NB*MC)
#define NBLK 320      // 8 FPS + 312 workers; LDS ~53.4KB -> 2 blocks/CU guaranteed (capacity 512)

typedef unsigned short u16;
typedef unsigned int   u32;
typedef unsigned long long u64;

static __device__ __forceinline__ float bf2f(u16 b){ return __uint_as_float(((u32)b)<<16); }
static __device__ __forceinline__ u16  f2bf(float f){
  u32 u = __float_as_uint(f);
  return (u16)((u + 0x7fffu + ((u>>16)&1u)) >> 16);
}
// Exact replica of reference distance: square each diff, sum as (x+y)+z, NO fma contraction.
static __device__ __forceinline__ float d2ref(float ax,float ay,float az,
                                              float bx,float by,float bz){
  float dx = ax-bx, dy = ay-by, dz = az-bz;
  return __fadd_rn(__fadd_rn(__fmul_rn(dx,dx), __fmul_rn(dy,dy)), __fmul_rn(dz,dz));
}
static __device__ __forceinline__ float wsum(float v){
  #pragma unroll
  for (int off = 32; off > 0; off >>= 1) v += __shfl_xor(v, off);
  return v;
}
static __device__ __forceinline__ float wmax(float v){
  #pragma unroll
  for (int off = 32; off > 0; off >>= 1) v = fmaxf(v, __shfl_xor(v, off));
  return v;
}
// One DPP max step: v = max(v, dpp_shuffle(v)). Pure VALU (no DS pipe).
template<int CTRL, int RMASK>
static __device__ __forceinline__ float dppmaxstep(float v){
  int t = __builtin_amdgcn_update_dpp(__float_as_int(v), __float_as_int(v),
                                      CTRL, RMASK, 0xF, false);
  return fmaxf(v, __int_as_float(t));
}
// Full wave64 max -> broadcast via readlane(63).
static __device__ __forceinline__ float wavemax_dpp(float v){
  v = dppmaxstep<0xB1, 0xF>(v);
  v = dppmaxstep<0x4E, 0xF>(v);
  v = dppmaxstep<0x141,0xF>(v);
  v = dppmaxstep<0x140,0xF>(v);
  v = dppmaxstep<0x142,0xA>(v);
  v = dppmaxstep<0x143,0xC>(v);
  return __int_as_float(__builtin_amdgcn_readlane(__float_as_int(v), 63));
}

// ---------------------------------------------------------------- fused front kernel
struct FpsL {
  float px[NPTS], py[NPTS], pz[NPTS];
  int   sIdx[MC];
  float4 cand[8];    // (d,x,y,z), double-buffered 2x4
  int    cIv[8];
};
struct WkL {
  u64   keys[CAP];        // ball-query sort keys
  float Hs[64*69];        // stage-1 H tile (odd pitch)
  int   nbrS[64];
  float red[4][32];
  float cxyz[3];
  int   scnt;
  int   task;
};
union FrontL { FpsL f; WkL w; };

__global__ __launch_bounds__(256) void k_front(const float* __restrict__ x,
                                               const float* __restrict__ pos,
                                               float* __restrict__ centf,
                                               float* __restrict__ out_cent,
                                               float* __restrict__ out_bsel,
                                               const float* __restrict__ W1,
                                               float* __restrict__ Spart,
                                               u16* __restrict__ y1g,
                                               int* __restrict__ cntpc,
                                               int* __restrict__ cnt_total,
                                               int* __restrict__ progress,
                                               int* __restrict__ taskctr) {
  __shared__ FrontL L;
  const int tid = threadIdx.x;

  if (blockIdx.x < NB) {
    // =========================== FPS producer: 4 waves, 16 pts/lane, ONE barrier/iter
    const int b = blockIdx.x;
    for (int i = tid; i < NPTS; i += 256) {
      size_t o = ((size_t)b*NPTS + i)*3;
      L.f.px[i] = pos[o]; L.f.py[i] = pos[o+1]; L.f.pz[i] = pos[o+2];
    }
    if (tid == 0) L.f.sIdx[0] = 0;
    __syncthreads();

    float cxr[16], cyr[16], czr[16], dist[16];
    #pragma unroll
    for (int j = 0; j < 16; ++j) {
      int p = tid*16 + j;
      cxr[j] = L.f.px[p]; cyr[j] = L.f.py[p]; czr[j] = L.f.pz[p];
      dist[j] = 1e10f;
    }
    const int lane = tid & 63, w = tid >> 6;
    float qx = L.f.px[0], qy = L.f.py[0], qz = L.f.pz[0];
    if (tid == 0) {
      int r = b*MC;
      centf[r*3+0]=qx; centf[r*3+1]=qy; centf[r*3+2]=qz;
    }

    for (int it = 1; it < MC; ++it) {
      float bv = -1.f, bx = 0.f, by = 0.f, bz = 0.f; int bi = 0;
      #pragma unroll
      for (int j = 0; j < 16; ++j) {
        float d  = d2ref(cxr[j], cyr[j], czr[j], qx, qy, qz);
        float nd = fminf(dist[j], d);
        dist[j] = nd;
        if (nd > bv) { bv = nd; bi = tid*16 + j; bx = cxr[j]; by = cyr[j]; bz = czr[j]; }
      }
      // in-wave max (DPP, VALU-only); lowest winning lane = lowest index
      float gmax = wavemax_dpp(bv);
      u64 mm = __ballot(bv == gmax);
      int wl = __ffsll((unsigned long long)mm) - 1;
      const int base = (it & 1) * 4;
      if (lane == wl) {
        L.f.cand[base + w] = make_float4(gmax, bx, by, bz);
        L.f.cIv[base + w]  = bi;
      }
      __syncthreads();
      // every wave resolves the 4 candidates redundantly (no second barrier)
      float4 cq = L.f.cand[base + (lane & 3)];
      float dm = cq.x;
      dm = dppmaxstep<0xB1, 0xF>(dm);    // quad_perm [1,0,3,2]
      dm = dppmaxstep<0x4E, 0xF>(dm);    // quad_perm [2,3,0,1] -> quad-max everywhere
      u64 m2 = __ballot(cq.x == dm);
      int wc = (__ffsll((unsigned long long)m2) - 1) & 3;  // lowest cand idx = lowest wave = lowest index
      float4 nq = L.f.cand[base + wc];   // broadcast LDS read of the winner
      qx = nq.y; qy = nq.z; qz = nq.w;
      if (tid == 0) {
        int r = b*MC + it;
        centf[r*3+0]=qx; centf[r*3+1]=qy; centf[r*3+2]=qz;
        L.f.sIdx[it] = L.f.cIv[base + wc];
        if ((it & 15) == 15)
          __hip_atomic_store(progress + b, it + 1, __ATOMIC_RELEASE, __HIP_MEMORY_SCOPE_AGENT);
      }
    }
    __syncthreads();
    // epilogue: out_cent / out_bsel from sIdx (off the critical path)
    for (int m2 = tid; m2 < MC; m2 += 256) {
      int i = L.f.sIdx[m2];
      int r = b*MC + m2;
      out_cent[r*3+0] = L.f.px[i]; out_cent[r*3+1] = L.f.py[i]; out_cent[r*3+2] = L.f.pz[i];
      out_bsel[r] = (float)b;
    }
    return;
  }

  // =========================== persistent workers: ball query + stage-1 per centroid
  for (;;) {
    if (tid == 0) {
      int t = atomicAdd(taskctr, 1);
      L.w.task = t;
      if (t < NTASK) {
        int m = t >> 3, b = t & 7;
        while (__hip_atomic_load(progress + b, __ATOMIC_ACQUIRE, __HIP_MEMORY_SCOPE_AGENT) < m + 1)
          __builtin_amdgcn_s_sleep(8);
        int bm = b*MC + m;
        L.w.cxyz[0] = __hip_atomic_load(centf + bm*3 + 0, __ATOMIC_RELAXED, __HIP_MEMORY_SCOPE_AGENT);
        L.w.cxyz[1] = __hip_atomic_load(centf + bm*3 + 1, __ATOMIC_RELAXED, __HIP_MEMORY_SCOPE_AGENT);
        L.w.cxyz[2] = __hip_atomic_load(centf + bm*3 + 2, __ATOMIC_RELAXED, __HIP_MEMORY_SCOPE_AGENT);
      }
      L.w.scnt = 0;
    }
    __syncthreads();
    const int t = L.w.task;
    if (t >= NTASK) return;
    const int m = t >> 3, b = t & 7, bm = b*MC + m;
    const float cx = L.w.cxyz[0], cy = L.w.cxyz[1], cz = L.w.cxyz[2];

    // ---- ball query (exact ref semantics)
    for (int i = tid; i < NPTS; i += 256) {
      size_t o = ((size_t)b*NPTS + i)*3;
      float d = d2ref(cx, cy, cz, pos[o], pos[o+1], pos[o+2]);
      if (d <= 0.04f) {
        int p = atomicAdd(&L.w.scnt, 1);
        if (p < CAP) L.w.keys[p] = ((u64)__float_as_uint(d) << 32) | (u32)i;
      }
    }
    __syncthreads();
    int n = L.w.scnt; if (n > CAP) n = CAP;
    int P = 64; while (P < n) P <<= 1;
    for (int i = n + tid; i < P; i += 256) L.w.keys[i] = ~0ull;
    __syncthreads();
    for (int ks = 2; ks <= P; ks <<= 1)
      for (int js = ks >> 1; js > 0; js >>= 1) {
        for (int i = tid; i < P; i += 256) {
          int l = i ^ js;
          if (l > i) {
            u64 a = L.w.keys[i], c = L.w.keys[l];
            bool up = ((i & ks) == 0);
            if ((a > c) == up) { L.w.keys[i] = c; L.w.keys[l] = a; }
          }
        }
        __syncthreads();
      }
    const int c = n < KNB ? n : KNB;
    if (tid < KNB) L.w.nbrS[tid] = (tid < c) ? (int)(u32)(L.w.keys[tid] & 0xffffffffu) : 0;
    if (tid == 0) { cntpc[bm] = c; atomicAdd(cnt_total, c); }
    __syncthreads();

    // ---- stage-1: H = [x_j, p_j - c_i] (64x67) staged in LDS
    {
      const int ge = tid >> 2, qb = tid & 3;
      const float4* xr = (const float4*)(x + ((size_t)(b*NPTS + L.w.nbrS[ge]))*CINV);
      #pragma unroll
      for (int rep = 0; rep < 4; ++rep) {
        int q = qb + rep*4;
        float4 v = xr[q];
        float* d = L.w.Hs + ge*69 + q*4;
        d[0] = v.x; d[1] = v.y; d[2] = v.z; d[3] = v.w;
      }
    }
    if (tid < 64) {
      int row = b*NPTS + L.w.nbrS[tid];
      L.w.Hs[tid*69+64] = pos[(size_t)row*3+0] - cx;
      L.w.Hs[tid*69+65] = pos[(size_t)row*3+1] - cy;
      L.w.Hs[tid*69+66] = pos[(size_t)row*3+2] - cz;
    }
    __syncthreads();

    // ---- GEMM: thread = (edge, col of 16 ch); W via wave-uniform SCALAR loads (SMEM pipe)
    const int edge = tid & 63;
    const int col  = __builtin_amdgcn_readfirstlane(tid >> 6);
    float acc[16];
    #pragma unroll
    for (int j = 0; j < 16; ++j) acc[j] = 0.f;
    const float* hrow = L.w.Hs + edge*69;
    const float* wcol = W1 + col*16;
    for (int k = 0; k < K1; ++k) {
      float hk = hrow[k];
      const float4* w4 = (const float4*)(wcol + k*CH1);
      #pragma unroll
      for (int q = 0; q < 4; ++q) {
        float4 wv = w4[q];
        acc[q*4+0] = fmaf(hk, wv.x, acc[q*4+0]);
        acc[q*4+1] = fmaf(hk, wv.y, acc[q*4+1]);
        acc[q*4+2] = fmaf(hk, wv.z, acc[q*4+2]);
        acc[q*4+3] = fmaf(hk, wv.w, acc[q*4+3]);
      }
    }
    const bool valid = edge < c;
    #pragma unroll
    for (int j = 0; j < 16; ++j) acc[j] = valid ? acc[j] : 0.f;
    u32* dst = (u32*)(y1g + ((size_t)bm*64 + edge)*CH1 + col*16);
    #pragma unroll
    for (int j = 0; j < 8; ++j)
      dst[j] = (u32)f2bf(acc[2*j]) | ((u32)f2bf(acc[2*j+1]) << 16);
    #pragma unroll
    for (int j = 0; j < 16; ++j) {
      float s = wsum(acc[j]);
      float q = wsum(acc[j]*acc[j]);
      if (edge == 0) { L.w.red[col][j] = s; L.w.red[col][16+j] = q; }
    }
    __syncthreads();
    const int slot = bm & (NSLOT-1);
    if (tid < 64)  atomicAdd(&Spart[slot*256 + tid], L.w.red[tid>>4][tid&15]);
    else if (tid < 128) {
      int cc = tid - 64;
      atomicAdd(&Spart[slot*256 + 128 + cc], L.w.red[cc>>4][16 + (cc&15)]);
    }
    // top-of-loop __syncthreads() isolates this task's LDS reads from next task's writes
  }
}

// ---------------------------------------------------------------- stage 2: relu(bn1(y1)) @ W2
__global__ __launch_bounds__(256) void k_s2(const u16* __restrict__ y1g,
                                            const float* __restrict__ SC,
                                            const float* __restrict__ W2,
                                            const int* __restrict__ cntpc,
                                            float* __restrict__ Spart,
                                            u16* __restrict__ y2g) {
  __shared__ float Hs[64*65];
  __shared__ float ABs[128];
  __shared__ float red[4][32];
  __shared__ int   cntS;
  const int tid = threadIdx.x, bm = blockIdx.x;
  if (tid == 0) cntS = cntpc[bm];
  if (tid < 128) ABs[tid] = SC[tid];            // A1(64) B1(64)
  __syncthreads();
  {
    const u32* yt = (const u32*)y1g + (size_t)bm*2048;  // 64 edges * 32 u32
    #pragma unroll
    for (int rep = 0; rep < 8; ++rep) {
      int g = rep*256 + tid;
      int e = g >> 5, c2 = g & 31, ch = c2*2;
      u32 v = yt[g];
      float lo = fmaxf(fmaf(bf2f((u16)(v & 0xffff)), ABs[ch],   ABs[64+ch]),   0.f);
      float hi = fmaxf(fmaf(bf2f((u16)(v >> 16)),    ABs[ch+1], ABs[64+ch+1]), 0.f);
      Hs[e*65 + ch] = lo; Hs[e*65 + ch + 1] = hi;
    }
  }
  __syncthreads();

  const int edge = tid & 63;
  const int col  = __builtin_amdgcn_readfirstlane(tid >> 6);
  float acc[16];
  #pragma unroll
  for (int j = 0; j < 16; ++j) acc[j] = 0.f;
  const float* hrow = Hs + edge*65;
  const float* wcol = W2 + col*16;
  for (int k = 0; k < CH1; ++k) {
    float hk = hrow[k];
    const float4* w4 = (const float4*)(wcol + k*CH2);
    #pragma unroll
    for (int q = 0; q < 4; ++q) {
      float4 wv = w4[q];
      acc[q*4+0] = fmaf(hk, wv.x, acc[q*4+0]);
      acc[q*4+1] = fmaf(hk, wv.y, acc[q*4+1]);
      acc[q*4+2] = fmaf(hk, wv.z, acc[q*4+2]);
      acc[q*4+3] = fmaf(hk, wv.w, acc[q*4+3]);
    }
  }
  const bool valid = edge < cntS;
  #pragma unroll
  for (int j = 0; j < 16; ++j) acc[j] = valid ? acc[j] : 0.f;
  u32* dst = (u32*)(y2g + ((size_t)bm*64 + edge)*CH2 + col*16);
  #pragma unroll
  for (int j = 0; j < 8; ++j)
    dst[j] = (u32)f2bf(acc[2*j]) | ((u32)f2bf(acc[2*j+1]) << 16);
  #pragma unroll
  for (int j = 0; j < 16; ++j) {
    float s = wsum(acc[j]);
    float q = wsum(acc[j]*acc[j]);
    if (edge == 0) { red[col][j] = s; red[col][16+j] = q; }
  }
  __syncthreads();
  const int slot = bm & (NSLOT-1);
  if (tid < 64)  atomicAdd(&Spart[slot*256 + tid], red[tid>>4][tid&15]);
  else if (tid < 128) {
    int c = tid - 64;
    atomicAdd(&Spart[slot*256 + 128 + c], red[c>>4][16 + (c&15)]);
  }
}

// ---------------------------------------------------------------- stage 3: relu(bn2(y2)) @ W3
template<bool STORE>
__global__ __launch_bounds__(256) void k_s3(const u16* __restrict__ y2g,
                                            const float* __restrict__ SC,
                                            const float* __restrict__ W3,
                                            const int* __restrict__ cntpc,
                                            float* __restrict__ Spart,
                                            u16* __restrict__ y3g,
                                            float* __restrict__ out0) {
  __shared__ float Hs[64*65];
  __shared__ float ABs[128];
  __shared__ float red[4][64];
  __shared__ int   cntS;
  const int tid = threadIdx.x, bm = blockIdx.x;
  if (tid == 0) cntS = cntpc[bm];
  if (tid < 128) ABs[tid] = SC[128 + tid];      // A2(64) B2(64)
  __syncthreads();
  {
    const u32* yt = (const u32*)y2g + (size_t)bm*2048;
    #pragma unroll
    for (int rep = 0; rep < 8; ++rep) {
      int g = rep*256 + tid;
      int e = g >> 5, c2 = g & 31, ch = c2*2;
      u32 v = yt[g];
      float lo = fmaxf(fmaf(bf2f((u16)(v & 0xffff)), ABs[ch],   ABs[64+ch]),   0.f);
      float hi = fmaxf(fmaf(bf2f((u16)(v >> 16)),    ABs[ch+1], ABs[64+ch+1]), 0.f);
      Hs[e*65 + ch] = lo; Hs[e*65 + ch + 1] = hi;
    }
  }
  __syncthreads();

  const int edge = tid & 63;
  const int col  = __builtin_amdgcn_readfirstlane(tid >> 6);  // owns 32 of 128 ch
  float acc[32];
  #pragma unroll
  for (int j = 0; j < 32; ++j) acc[j] = 0.f;
  const float* hrow = Hs + edge*65;
  const float* wcol = W3 + col*32;
  for (int k = 0; k < CH2; ++k) {
    float hk = hrow[k];
    const float4* w4 = (const float4*)(wcol + k*CH3);
    #pragma unroll
    for (int q = 0; q < 8; ++q) {
      float4 wv = w4[q];
      acc[q*4+0] = fmaf(hk, wv.x, acc[q*4+0]);
      acc[q*4+1] = fmaf(hk, wv.y, acc[q*4+1]);
      acc[q*4+2] = fmaf(hk, wv.z, acc[q*4+2]);
      acc[q*4+3] = fmaf(hk, wv.w, acc[q*4+3]);
    }
  }
  const bool valid = edge < cntS;
  #pragma unroll
  for (int j = 0; j < 32; ++j) acc[j] = valid ? acc[j] : 0.f;
  if constexpr (STORE) {
    u32* dst = (u32*)(y3g + ((size_t)bm*64 + edge)*CH3 + col*32);
    #pragma unroll
    for (int j = 0; j < 16; ++j)
      dst[j] = (u32)f2bf(acc[2*j]) | ((u32)f2bf(acc[2*j+1]) << 16);
  }
  #pragma unroll
  for (int j = 0; j < 32; ++j) {
    float s = wsum(acc[j]);
    float q = wsum(acc[j]*acc[j]);
    if (edge == 0) { red[col][j] = s; red[col][32+j] = q; }
  }
  __syncthreads();
  const int slot = bm & (NSLOT-1);
  if (tid < 128) atomicAdd(&Spart[slot*256 + tid], red[tid>>5][tid&31]);
  else {
    int c = tid - 128;
    atomicAdd(&Spart[slot*256 + 128 + c], red[c>>5][32 + (c&31)]);
  }
}

// ---------------------------------------------------------------- stage 4A: bn3+relu+maxpool from stored y3
__global__ __launch_bounds__(128) void k_s4(const u16* __restrict__ y3g,
                                            const float* __restrict__ SC,
                                            const int* __restrict__ cntpc,
                                            float* __restrict__ out0) {
  const int tid = threadIdx.x, bm = blockIdx.x;
  const int cnt = cntpc[bm];
  const float a = SC[256 + tid], b = SC[384 + tid];
  const u16* yr = y3g + (size_t)bm*64*CH3 + tid;
  float mx = -1e30f;
  for (int e = 0; e < cnt; ++e) {
    float v = bf2f(yr[e*CH3]);
    mx = fmaxf(mx, fmaxf(fmaf(v, a, b), 0.f));
  }
  out0[(size_t)bm*CH3 + tid] = mx;
}

// ---------------------------------------------------------------- stage 4B (fallback): recompute y3 from y2
__global__ __launch_bounds__(256) void k_s4r(const u16* __restrict__ y2g,
                                             const float* __restrict__ SC,
                                             const float* __restrict__ W3,
                                             const int* __restrict__ cntpc,
                                             float* __restrict__ out0) {
  __shared__ float Hs[64*65];
  __shared__ float ABs[128];
  __shared__ float AB3[256];
  __shared__ int   cntS;
  const int tid = threadIdx.x, bm = blockIdx.x;
  if (tid == 0) cntS = cntpc[bm];
  if (tid < 128) ABs[tid] = SC[128 + tid];
  ((float*)AB3)[tid] = SC[256 + tid];   // A3(128) B3(128)
  __syncthreads();
  {
    const u32* yt = (const u32*)y2g + (size_t)bm*2048;
    #pragma unroll
    for (int rep = 0; rep < 8; ++rep) {
      int g = rep*256 + tid;
      int e = g >> 5, c2 = g & 31, ch = c2*2;
      u32 v = yt[g];
      float lo = fmaxf(fmaf(bf2f((u16)(v & 0xffff)), ABs[ch],   ABs[64+ch]),   0.f);
      float hi = fmaxf(fmaf(bf2f((u16)(v >> 16)),    ABs[ch+1], ABs[64+ch+1]), 0.f);
      Hs[e*65 + ch] = lo; Hs[e*65 + ch + 1] = hi;
    }
  }
  __syncthreads();
  const int edge = tid & 63;
  const int col  = __builtin_amdgcn_readfirstlane(tid >> 6);
  float acc[32];
  #pragma unroll
  for (int j = 0; j < 32; ++j) acc[j] = 0.f;
  const float* hrow = Hs + edge*65;
  const float* wcol = W3 + col*32;
  for (int k = 0; k < CH2; ++k) {
    float hk = hrow[k];
    const float4* w4 = (const float4*)(wcol + k*CH3);
    #pragma unroll
    for (int q = 0; q < 8; ++q) {
      float4 wv = w4[q];
      acc[q*4+0] = fmaf(hk, wv.x, acc[q*4+0]);
      acc[q*4+1] = fmaf(hk, wv.y, acc[q*4+1]);
      acc[q*4+2] = fmaf(hk, wv.z, acc[q*4+2]);
      acc[q*4+3] = fmaf(hk, wv.w, acc[q*4+3]);
    }
  }
  const bool valid = edge < cntS;
  #pragma unroll
  for (int j = 0; j < 32; ++j) {
    int ch = col*32 + j;
    float h = fmaxf(fmaf(acc[j], AB3[ch], AB3[128+ch]), 0.f);
    float mx = wmax(valid ? h : -1e30f);
    if (edge == 0) out0[(size_t)bm*CH3 + ch] = mx;
  }
}

// ---------------------------------------------------------------- finalize
__global__ void k_finalize(const float* __restrict__ Spart,
                           const float* __restrict__ g, const float* __restrict__ bb,
                           const int* __restrict__ cnt_total,
                           float* __restrict__ Aout, float* __restrict__ Bout, int C) {
  int c = threadIdx.x;
  if (c < C) {
    float s = 0.f, q = 0.f;
    for (int sl = 0; sl < NSLOT; ++sl) {
      s += Spart[sl*256 + c];
      q += Spart[sl*256 + 128 + c];
    }
    float n = (float)(*cnt_total); if (n < 1.f) n = 1.f;
    float mu  = s / n;
    float var = q / n - mu*mu; if (var < 0.f) var = 0.f;
    float inv = 1.0f / sqrtf(var + 1e-5f);
    float a = g[c] * inv;
    Aout[c] = a;
    Bout[c] = bb[c] - mu*a;
  }
}

// ---------------------------------------------------------------- host
extern "C" void kernel_launch(void* const* d_in, const int* in_sizes, int n_in,
                              void* d_out, int out_size, void* d_ws, size_t ws_size,
                              hipStream_t stream) {
  (void)in_sizes; (void)n_in; (void)out_size;
  const float* x   = (const float*)d_in[0];
  const float* pos = (const float*)d_in[1];
  const float* W1  = (const float*)d_in[3];
  const float* g1  = (const float*)d_in[4];
  const float* b1  = (const float*)d_in[5];
  const float* W2  = (const float*)d_in[6];
  const float* g2  = (const float*)d_in[7];
  const float* b2  = (const float*)d_in[8];
  const float* W3  = (const float*)d_in[9];
  const float* g3  = (const float*)d_in[10];
  const float* b3  = (const float*)d_in[11];

  float* out0     = (float*)d_out;
  float* out_cent = out0 + (size_t)NB*MC*CH3;
  float* out_bsel = out_cent + (size_t)NB*MC*3;

  char* base = (char*)d_ws;
  size_t off = 0;
  auto carve = [&](size_t bytes) -> char* {
    char* p = base + off;
    off = (off + bytes + 255) & ~(size_t)255;
    return p;
  };
  float* centf = (float*)carve(sizeof(float)*NB*MC*3);
  int*   cntpc = (int*)  carve(sizeof(int)*NB*MC);
  char*  zeroblk = carve(256 + 3*NSLOT*256*sizeof(float));
  int*   cnt_total = (int*)zeroblk;
  int*   taskctr   = cnt_total + 1;
  int*   progress  = cnt_total + 2;    // 8 ints
  float* Sp1 = (float*)(zeroblk + 256);
  float* Sp2 = Sp1 + NSLOT*256;
  float* Sp3 = Sp2 + NSLOT*256;
  float* SC = (float*)carve(512*sizeof(float));  // A1 B1 A2 B2 A3(128) B3(128)
  u16* y1g = (u16*)carve((size_t)NE*CH1*2);
  u16* y2g = (u16*)carve((size_t)NE*CH2*2);
  u16* y3g = (u16*)carve((size_t)NE*CH3*2);
  bool have_y3 = (ws_size >= off);

  hipMemsetAsync(zeroblk, 0, 256 + 3*NSLOT*256*sizeof(float), stream);
  k_front<<<NBLK, 256, 0, stream>>>(x, pos, centf, out_cent, out_bsel,
                                    W1, Sp1, y1g, cntpc, cnt_total, progress, taskctr);
  k_finalize<<<1, 128, 0, stream>>>(Sp1, g1, b1, cnt_total, SC + 0,   SC + 64,  CH1);
  dim3 sg(NB*MC), sb(256);
  k_s2<<<sg, sb, 0, stream>>>(y1g, SC, W2, cntpc, Sp2, y2g);
  k_finalize<<<1, 128, 0, stream>>>(Sp2, g2, b2, cnt_total, SC + 128, SC + 192, CH2);
  if (have_y3) {
    k_s3<true><<<sg, sb, 0, stream>>>(y2g, SC, W3, cntpc, Sp3, y3g, out0);
    k_finalize<<<1, 128, 0, stream>>>(Sp3, g3, b3, cnt_total, SC + 256, SC + 384, CH3);
    k_s4<<<sg, 128, 0, stream>>>(y3g, SC, cntpc, out0);
  } else {
    k_s3<false><<<sg, sb, 0, stream>>>(y2g, SC, W3, cntpc, Sp3, y3g, out0);
    k_finalize<<<1, 128, 0, stream>>>(Sp3, g3, b3, cnt_total, SC + 256, SC + 384, CH3);
    k_s4r<<<sg, sb, 0, stream>>>(y2g, SC, W3, cntpc, out0);
  }
}